// Round 1
// baseline (363.836 us; speedup 1.0000x reference)
//
#include <hip/hip_runtime.h>
#include <math.h>

#define NGRAPH 64
#define POOL_CHUNKS 32
#define SCAN_BLK 1024

typedef short short8 __attribute__((ext_vector_type(8)));
typedef float floatx4 __attribute__((ext_vector_type(4)));

__device__ inline unsigned pack_bf16x2(float a, float b) {
    unsigned ua = __float_as_uint(a);
    unsigned ub = __float_as_uint(b);
    ua = (ua + 0x7fffu + ((ua >> 16) & 1u)) >> 16;   // RNE
    ub = (ub + 0x7fffu + ((ub >> 16) & 1u)) >> 16;
    return ua | (ub << 16);
}
__device__ inline unsigned short bf16_1(float a) {
    unsigned ua = __float_as_uint(a);
    return (unsigned short)((ua + 0x7fffu + ((ua >> 16) & 1u)) >> 16);
}
__device__ inline float bf16lo(unsigned u) { return __uint_as_float(u << 16); }
__device__ inline float bf16hi(unsigned u) { return __uint_as_float(u & 0xffff0000u); }

// All 128-wide bf16 intermediates use QUARTER-MAJOR layout: [4][N][32] bf16.
// Quarter q of node n lives at ((size_t)q * N + n) * 32 .. +31.
// Each 3.2 MB quarter fits in one XCD's 4 MB L2 -> agg gathers become L2 hits.

// ---------------- fused: W2/W3 transpose+bf16-pack (blocks 0..31) + degree count (rest) ----------------

__global__ void pack_count(const int* __restrict__ dst, int E, int* __restrict__ cnt,
                           const float* __restrict__ W2, const float* __restrict__ W3,
                           unsigned* __restrict__ Wt2, unsigned* __restrict__ Wt3) {
    if (blockIdx.x < 32) {
        int b = blockIdx.x;
        const float* W = (b < 16) ? W2 : W3;
        unsigned* Wt = (b < 16) ? Wt2 : Wt3;
        b &= 15;
        int bk = b & 3, bn = b >> 2;
        __shared__ float s[32][33];
        int tx = threadIdx.x & 31, ty = threadIdx.x >> 5;
#pragma unroll
        for (int r = 0; r < 4; ++r)
            s[r * 8 + ty][tx] = W[(bk * 32 + r * 8 + ty) * 128 + bn * 32 + tx];
        __syncthreads();
        int t16 = threadIdx.x & 15, tn = threadIdx.x >> 4;
#pragma unroll
        for (int pass = 0; pass < 2; ++pass) {
            int nl = pass * 16 + tn;
            unsigned pk = pack_bf16x2(s[2 * t16][nl], s[2 * t16 + 1][nl]);
            Wt[(bn * 32 + nl) * 64 + bk * 16 + t16] = pk;
        }
    } else {
        int e = (blockIdx.x - 32) * blockDim.x + threadIdx.x;
        if (e < E) atomicAdd(&cnt[dst[e]], 1);
    }
}

// ---- multi-block exclusive scan (fused dinv/y) ----

__global__ __launch_bounds__(SCAN_BLK) void scan_phase1(const int* __restrict__ cnt,
                                                        const float* __restrict__ x,
                                                        int* __restrict__ row_ptr,
                                                        int* __restrict__ bsum,
                                                        float* __restrict__ dinv,
                                                        float2* __restrict__ y, int N) {
    __shared__ int sm[SCAN_BLK];
    int i = blockIdx.x * SCAN_BLK + threadIdx.x;
    int v = (i < N) ? cnt[i] : 0;
    if (i < N) {
        float dv = rsqrtf((float)v + 1.0f);
        dinv[i] = dv;
        float2 xv = ((const float2*)x)[i];
        y[i] = make_float2(xv.x * dv, xv.y * dv);
    }
    sm[threadIdx.x] = v;
    __syncthreads();
    for (int off = 1; off < SCAN_BLK; off <<= 1) {
        int t = (threadIdx.x >= (unsigned)off) ? sm[threadIdx.x - off] : 0;
        __syncthreads();
        sm[threadIdx.x] += t;
        __syncthreads();
    }
    if (i < N) row_ptr[i] = sm[threadIdx.x] - v;
    if (threadIdx.x == SCAN_BLK - 1) bsum[blockIdx.x] = sm[SCAN_BLK - 1];
}

__global__ __launch_bounds__(SCAN_BLK) void scan_phase2(int* __restrict__ bsum, int nb,
                                                        const int* __restrict__ batch, int N,
                                                        int* __restrict__ goff) {
    if (threadIdx.x <= NGRAPH) {
        int g = threadIdx.x;
        int lo = 0, hi = N;
        while (lo < hi) {
            int mid = (lo + hi) >> 1;
            if (batch[mid] < g) lo = mid + 1; else hi = mid;
        }
        goff[g] = lo;
    }
    __shared__ int sm[SCAN_BLK];
    int v = (threadIdx.x < (unsigned)nb) ? bsum[threadIdx.x] : 0;
    sm[threadIdx.x] = v;
    __syncthreads();
    for (int off = 1; off < SCAN_BLK; off <<= 1) {
        int t = (threadIdx.x >= (unsigned)off) ? sm[threadIdx.x - off] : 0;
        __syncthreads();
        sm[threadIdx.x] += t;
        __syncthreads();
    }
    if (threadIdx.x < (unsigned)nb) bsum[threadIdx.x] = sm[threadIdx.x] - v;
}

__global__ __launch_bounds__(SCAN_BLK) void scan_phase3(int* __restrict__ row_ptr,
                                                        const int* __restrict__ bsum,
                                                        int N, int E) {
    int i = blockIdx.x * SCAN_BLK + threadIdx.x;
    if (i < N) row_ptr[i] += bsum[blockIdx.x];
    if (i == 0) row_ptr[N] = E;
}

// reverse-fill using cnt itself (dead after scan)
__global__ void fill_kernel(const int* __restrict__ src, const int* __restrict__ dst, int E,
                            const int* __restrict__ row_ptr, int* __restrict__ cnt,
                            int* __restrict__ col) {
    int e = blockIdx.x * blockDim.x + threadIdx.x;
    if (e < E) {
        int d = dst[e];
        int p = row_ptr[d] + atomicSub(&cnt[d], 1) - 1;
        col[p] = src[e];
    }
}

// ---------------- layer 1 fused: z = agg(y) ; h1 = tanh(z @ W1 + b1) (bf16, quarter-major out) --------

__global__ __launch_bounds__(256) void agg_x_t1(const float2* __restrict__ y,
                                                const int* __restrict__ row_ptr,
                                                const int* __restrict__ col,
                                                const float* __restrict__ dinv,
                                                const float* __restrict__ W1,
                                                const float* __restrict__ b1,
                                                unsigned short* __restrict__ h, int N) {
    __shared__ float4 sW[64];     // W1[2][128]
    __shared__ float4 sb[32];     // b1[128]
    __shared__ float2 zs[256];
    if (threadIdx.x < 64) sW[threadIdx.x] = ((const float4*)W1)[threadIdx.x];
    if (threadIdx.x < 32) sb[threadIdx.x] = ((const float4*)b1)[threadIdx.x];

    int v = blockIdx.x * 256 + threadIdx.x;
    float2 zv = make_float2(0.f, 0.f);
    if (v < N) {
        int s = row_ptr[v], e = row_ptr[v + 1];
        float2 a0 = y[v];
        float2 a1 = make_float2(0.f, 0.f);
        float2 a2 = make_float2(0.f, 0.f);
        float2 a3 = make_float2(0.f, 0.f);
        int j = s;
        for (; j + 4 <= e; j += 4) {
            int u0 = col[j], u1 = col[j + 1], u2 = col[j + 2], u3 = col[j + 3];
            float2 v0 = y[u0], v1 = y[u1], v2 = y[u2], v3 = y[u3];
            a0.x += v0.x; a0.y += v0.y;
            a1.x += v1.x; a1.y += v1.y;
            a2.x += v2.x; a2.y += v2.y;
            a3.x += v3.x; a3.y += v3.y;
        }
        for (; j < e; ++j) {
            float2 vv = y[col[j]];
            a0.x += vv.x; a0.y += vv.y;
        }
        float dv = dinv[v];
        zv = make_float2(dv * (a0.x + a1.x + a2.x + a3.x),
                         dv * (a0.y + a1.y + a2.y + a3.y));
    }
    zs[threadIdx.x] = zv;
    __syncthreads();

    int q = threadIdx.x & 31;          // col quad (4 cols)
    int rsub = threadIdx.x >> 5;       // 0..7
    float4 w0 = sW[q];
    float4 w1 = sW[32 + q];
    float4 b = sb[q];
    size_t qoff = (size_t)(q >> 3) * N;  // quarter base (rows)
#pragma unroll 4
    for (int pass = 0; pass < 32; ++pass) {
        int local = pass * 8 + rsub;
        int row = blockIdx.x * 256 + local;
        if (row >= N) break;
        float2 z = zs[local];
        float ox = tanhf(fmaf(z.x, w0.x, fmaf(z.y, w1.x, b.x)));
        float oy = tanhf(fmaf(z.x, w0.y, fmaf(z.y, w1.y, b.y)));
        float oz = tanhf(fmaf(z.x, w0.z, fmaf(z.y, w1.z, b.z)));
        float ow = tanhf(fmaf(z.x, w0.w, fmaf(z.y, w1.w, b.w)));
        uint2 pk;
        pk.x = pack_bf16x2(ox, oy);
        pk.y = pack_bf16x2(oz, ow);
        ((uint2*)h)[(qoff + row) * 8 + (q & 7)] = pk;
    }
}

// ---------------- MFMA GEMM: t[4][N][32](bf16) = (A[4][N][32](bf16) @ W) * dinv ----------------

__global__ __launch_bounds__(256) void gemm_mfma(const unsigned short* __restrict__ A,
                                                 const unsigned* __restrict__ Wt,
                                                 const float* __restrict__ dinv,
                                                 unsigned short* __restrict__ t, int N) {
    __shared__ unsigned sW[128 * 68];
    const uint4* Wt4 = (const uint4*)Wt;
    for (int i = threadIdx.x; i < 2048; i += 256) {
        int n = i >> 4, c = i & 15;
        *(uint4*)&sW[n * 68 + c * 4] = Wt4[i];
    }
    __syncthreads();
    int w = threadIdx.x >> 6;
    int l = threadIdx.x & 63;
    int lm = l & 15;
    int q4 = l >> 4;
    int k8 = q4 * 8;

    floatx4 acc[2][8];
#pragma unroll
    for (int i = 0; i < 2; ++i)
#pragma unroll
        for (int j = 0; j < 8; ++j) acc[i][j] = (floatx4){0.f, 0.f, 0.f, 0.f};

    int rowbase = blockIdx.x * 128 + w * 32;
#pragma unroll
    for (int ks = 0; ks < 4; ++ks) {
        // A element [r][ks*32 + k8 ..] lives in quarter ks at offset k8
        short8 a[2];
#pragma unroll
        for (int mt = 0; mt < 2; ++mt) {
            int r = min(rowbase + mt * 16 + lm, N - 1);
            a[mt] = *(const short8*)(A + ((size_t)ks * N + r) * 32 + k8);
        }
#pragma unroll
        for (int nt = 0; nt < 8; ++nt) {
            short8 b = *(const short8*)&sW[(nt * 16 + lm) * 68 + ks * 16 + q4 * 4];
#pragma unroll
            for (int mt = 0; mt < 2; ++mt)
                acc[mt][nt] = __builtin_amdgcn_mfma_f32_16x16x32_bf16(a[mt], b, acc[mt][nt], 0, 0, 0);
        }
    }

#pragma unroll
    for (int mt = 0; mt < 2; ++mt) {
#pragma unroll
        for (int reg = 0; reg < 4; ++reg) {
            int gr = rowbase + mt * 16 + q4 * 4 + reg;
            if (gr >= N) continue;
            float dv = dinv[gr];
#pragma unroll
            for (int nt = 0; nt < 8; ++nt) {
                // col c = nt*16+lm -> quarter nt>>1, offset (nt&1)*16+lm
                t[((size_t)(nt >> 1) * N + gr) * 32 + (nt & 1) * 16 + lm] =
                    bf16_1(acc[mt][nt][reg] * dv);
            }
        }
    }
}

// ---------------- aggregation: one node per wave, ONE FEATURE QUARTER per block (blockIdx.y) ----------
// 16 edge-slots (i=lane>>2) x 4 col-lanes (q=lane&3, 8 bf16 each = 16B).
// Gather table per quarter = 3.2 MB -> resident in each XCD's 4 MB L2.
// x-fastest dispatch order => whole device works one quarter at a time.

__global__ __launch_bounds__(256) void agg_kernel(const unsigned short* __restrict__ t,
                                                  const int* __restrict__ row_ptr,
                                                  const int* __restrict__ col,
                                                  const float* __restrict__ dinv,
                                                  const float* __restrict__ bias,
                                                  unsigned short* __restrict__ out, int N) {
    int wave = threadIdx.x >> 6;
    int lane = threadIdx.x & 63;
    int i = lane >> 2;                 // edge slot 0..15
    int q = lane & 3;                  // col slot (8 bf16)
    int qt = blockIdx.y;               // feature quarter 0..3
    int node = blockIdx.x * 4 + wave;
    if (node >= N) return;
    int s = row_ptr[node];
    int deg = row_ptr[node + 1] - s;
    const uint4* t4 = (const uint4*)t;
    size_t qbase = (size_t)qt * N;

    float a[8];
#pragma unroll
    for (int k = 0; k < 8; ++k) a[k] = 0.f;
    if (i == 0) {                      // self term (once, via slot 0)
        uint4 v = t4[(qbase + node) * 4 + q];
        a[0] = bf16lo(v.x); a[1] = bf16hi(v.x);
        a[2] = bf16lo(v.y); a[3] = bf16hi(v.y);
        a[4] = bf16lo(v.z); a[5] = bf16hi(v.z);
        a[6] = bf16lo(v.w); a[7] = bf16hi(v.w);
    }
    int j = 0;
    for (; j + 16 <= deg; j += 16) {   // 16 edges per trip, all slots valid
        int u = col[s + j + i];
        uint4 v = t4[(qbase + u) * 4 + q];
        a[0] += bf16lo(v.x); a[1] += bf16hi(v.x);
        a[2] += bf16lo(v.y); a[3] += bf16hi(v.y);
        a[4] += bf16lo(v.z); a[5] += bf16hi(v.z);
        a[6] += bf16lo(v.w); a[7] += bf16hi(v.w);
    }
    if (j + i < deg) {                 // predicated tail (<=15 edges)
        int u = col[s + j + i];
        uint4 v = t4[(qbase + u) * 4 + q];
        a[0] += bf16lo(v.x); a[1] += bf16hi(v.x);
        a[2] += bf16lo(v.y); a[3] += bf16hi(v.y);
        a[4] += bf16lo(v.z); a[5] += bf16hi(v.z);
        a[6] += bf16lo(v.w); a[7] += bf16hi(v.w);
    }
#pragma unroll
    for (int k = 0; k < 8; ++k) {      // reduce across 16 edge slots (stride 4 lanes)
        float v = a[k];
        v += __shfl_xor(v, 4, 64);
        v += __shfl_xor(v, 8, 64);
        v += __shfl_xor(v, 16, 64);
        v += __shfl_xor(v, 32, 64);
        a[k] = v;
    }
    if (i == 0) {
        float dv = dinv[node];
        float4 b0 = ((const float4*)bias)[qt * 8 + q * 2];
        float4 b1 = ((const float4*)bias)[qt * 8 + q * 2 + 1];
        uint4 pk;
        pk.x = pack_bf16x2(tanhf(fmaf(dv, a[0], b0.x)), tanhf(fmaf(dv, a[1], b0.y)));
        pk.y = pack_bf16x2(tanhf(fmaf(dv, a[2], b0.z)), tanhf(fmaf(dv, a[3], b0.w)));
        pk.z = pack_bf16x2(tanhf(fmaf(dv, a[4], b1.x)), tanhf(fmaf(dv, a[5], b1.y)));
        pk.w = pack_bf16x2(tanhf(fmaf(dv, a[6], b1.z)), tanhf(fmaf(dv, a[7], b1.w)));
        ((uint4*)out)[(qbase + node) * 4 + q] = pk;
    }
}

// ---------------- pooling (bf16 h, quarter-major) + fused output head ----------------

__global__ __launch_bounds__(128) void pool_partial(const unsigned short* __restrict__ h,
                                                    const int* __restrict__ goff,
                                                    float* __restrict__ part, int N) {
    int g = blockIdx.x;
    int c = blockIdx.y;
    int j = threadIdx.x;
    int s = goff[g], e = goff[g + 1];
    int cnt = e - s;
    int per = (cnt + POOL_CHUNKS - 1) / POOL_CHUNKS;
    int ps = s + c * per;
    int pe = min(ps + per, e);
    size_t qoff = (size_t)(j >> 5) * N;
    int jq = j & 31;
    float mx = -3.402823466e+38f, sm = 0.f;
    for (int n = ps; n < pe; ++n) {
        float v = __uint_as_float(((unsigned)h[(qoff + n) * 32 + jq]) << 16);
        mx = fmaxf(mx, v);
        sm += v;
    }
    float* dst = part + ((size_t)g * POOL_CHUNKS + c) * 256;
    dst[j] = mx;
    dst[128 + j] = sm;
}

__global__ __launch_bounds__(128) void pool_final(const float* __restrict__ part,
                                                  const int* __restrict__ goff,
                                                  const float* __restrict__ Wo,
                                                  const float* __restrict__ bo,
                                                  float* __restrict__ out) {
    __shared__ float p[256];
    int g = blockIdx.x;
    int j = threadIdx.x;
    float mx = -3.402823466e+38f, sm = 0.f;
    const float* base = part + (size_t)g * POOL_CHUNKS * 256;
#pragma unroll 4
    for (int c = 0; c < POOL_CHUNKS; ++c) {
        mx = fmaxf(mx, base[c * 256 + j]);
        sm += base[c * 256 + 128 + j];
    }
    int cnt = goff[g + 1] - goff[g];
    p[j] = (cnt > 0) ? mx : 0.f;
    p[128 + j] = sm / fmaxf((float)cnt, 1.f);
    __syncthreads();
    if (j < 41) {
        float acc = bo[j];
        for (int k = 0; k < 256; ++k) acc = fmaf(p[k], Wo[k * 41 + j], acc);
        out[g * 41 + j] = tanhf(acc);
    }
}

// ---------------- launch ----------------

extern "C" void kernel_launch(void* const* d_in, const int* in_sizes, int n_in,
                              void* d_out, int out_size, void* d_ws, size_t ws_size,
                              hipStream_t stream) {
    const float* x   = (const float*)d_in[0];
    const int*   ei  = (const int*)d_in[1];
    const int* batch = (const int*)d_in[2];
    const float* W1  = (const float*)d_in[3];
    const float* b1  = (const float*)d_in[4];
    const float* W2  = (const float*)d_in[5];
    const float* b2  = (const float*)d_in[6];
    const float* W3  = (const float*)d_in[7];
    const float* b3  = (const float*)d_in[8];
    const float* Wo  = (const float*)d_in[9];
    const float* bo  = (const float*)d_in[10];
    float* outp = (float*)d_out;

    int N = in_sizes[2];
    int E = in_sizes[1] / 2;
    const int* src = ei;
    const int* dst = ei + E;

    char* p = (char*)d_ws;
    auto alloc = [&](size_t bytes) -> char* {
        char* q = p;
        p += (bytes + 255) & ~(size_t)255;
        return q;
    };
    unsigned short* t   = (unsigned short*)alloc((size_t)N * 128 * 2);  // bf16 gemm out [4][N][32]
    unsigned short* hb  = (unsigned short*)alloc((size_t)N * 128 * 2);  // bf16 h1 / h2  [4][N][32]
    unsigned short* h3b = (unsigned short*)alloc((size_t)N * 128 * 2);  // bf16 h3       [4][N][32]
    float* dinv   = (float*)alloc((size_t)N * 4);
    int*   cnt    = (int*)alloc((size_t)N * 4);
    int*   rowp   = (int*)alloc((size_t)(N + 1) * 4);
    int*   col    = (int*)alloc((size_t)E * 4);
    int*   goff   = (int*)alloc(65 * 4);
    float* part   = (float*)alloc((size_t)NGRAPH * POOL_CHUNKS * 256 * 4);
    float2* y     = (float2*)alloc((size_t)N * 8);
    unsigned* Wt2 = (unsigned*)alloc(128 * 64 * 4);
    unsigned* Wt3 = (unsigned*)alloc(128 * 64 * 4);
    int nscan = (N + SCAN_BLK - 1) / SCAN_BLK;
    int*   bsum   = (int*)alloc((size_t)nscan * 4);

    hipMemsetAsync(cnt, 0, (size_t)N * 4, stream);

    pack_count<<<32 + (E + 255) / 256, 256, 0, stream>>>(dst, E, cnt, W2, W3, Wt2, Wt3);
    scan_phase1<<<nscan, SCAN_BLK, 0, stream>>>(cnt, x, rowp, bsum, dinv, y, N);
    scan_phase2<<<1, SCAN_BLK, 0, stream>>>(bsum, nscan, batch, N, goff);
    scan_phase3<<<nscan, SCAN_BLK, 0, stream>>>(rowp, bsum, N, E);
    fill_kernel<<<(E + 255) / 256, 256, 0, stream>>>(src, dst, E, rowp, cnt, col);

    dim3 agrid((N + 3) / 4, 4);  // x = node blocks (fast), y = feature quarter (slow)

    // layer 1: fused agg(x) + transform -> h1 (bf16, quarter-major)
    agg_x_t1<<<(N + 255) / 256, 256, 0, stream>>>(y, rowp, col, dinv, W1, b1, hb, N);
    // layer 2
    gemm_mfma<<<(N + 127) / 128, 256, 0, stream>>>(hb, Wt2, dinv, t, N);
    agg_kernel<<<agrid, 256, 0, stream>>>(t, rowp, col, dinv, b2, hb, N);
    // layer 3
    gemm_mfma<<<(N + 127) / 128, 256, 0, stream>>>(hb, Wt3, dinv, t, N);
    agg_kernel<<<agrid, 256, 0, stream>>>(t, rowp, col, dinv, b3, h3b, N);

    // pool + fused head
    dim3 pgrid(NGRAPH, POOL_CHUNKS);
    pool_partial<<<pgrid, 128, 0, stream>>>(h3b, goff, part, N);
    pool_final<<<NGRAPH, 128, 0, stream>>>(part, goff, Wo, bo, outp);
}

// Round 2
// 277.916 us; speedup vs baseline: 1.3092x; 1.3092x over previous
//
#include <hip/hip_runtime.h>
#include <math.h>

#define NGRAPH 64
#define POOL_CHUNKS 32
#define SCAN_BLK 1024

typedef short short8 __attribute__((ext_vector_type(8)));
typedef float floatx4 __attribute__((ext_vector_type(4)));

__device__ inline unsigned pack_bf16x2(float a, float b) {
    unsigned ua = __float_as_uint(a);
    unsigned ub = __float_as_uint(b);
    ua = (ua + 0x7fffu + ((ua >> 16) & 1u)) >> 16;   // RNE
    ub = (ub + 0x7fffu + ((ub >> 16) & 1u)) >> 16;
    return ua | (ub << 16);
}
__device__ inline unsigned short bf16_1(float a) {
    unsigned ua = __float_as_uint(a);
    return (unsigned short)((ua + 0x7fffu + ((ua >> 16) & 1u)) >> 16);
}
__device__ inline float bf16lo(unsigned u) { return __uint_as_float(u << 16); }
__device__ inline float bf16hi(unsigned u) { return __uint_as_float(u & 0xffff0000u); }

// All 128-wide bf16 intermediates use QUARTER-MAJOR layout: [4][N][32] bf16.
// Quarter q of node n lives at ((size_t)q * N + n) * 32 .. +31.
// Each 3.2 MB quarter fits in one XCD's 4 MB L2 -> agg gathers become L2 hits.

// ---------------- fused: W2/W3 transpose+bf16-pack (blocks 0..31) + degree count (rest) ----------------

__global__ void pack_count(const int* __restrict__ dst, int E, int* __restrict__ cnt,
                           const float* __restrict__ W2, const float* __restrict__ W3,
                           unsigned* __restrict__ Wt2, unsigned* __restrict__ Wt3) {
    if (blockIdx.x < 32) {
        int b = blockIdx.x;
        const float* W = (b < 16) ? W2 : W3;
        unsigned* Wt = (b < 16) ? Wt2 : Wt3;
        b &= 15;
        int bk = b & 3, bn = b >> 2;
        __shared__ float s[32][33];
        int tx = threadIdx.x & 31, ty = threadIdx.x >> 5;
#pragma unroll
        for (int r = 0; r < 4; ++r)
            s[r * 8 + ty][tx] = W[(bk * 32 + r * 8 + ty) * 128 + bn * 32 + tx];
        __syncthreads();
        int t16 = threadIdx.x & 15, tn = threadIdx.x >> 4;
#pragma unroll
        for (int pass = 0; pass < 2; ++pass) {
            int nl = pass * 16 + tn;
            unsigned pk = pack_bf16x2(s[2 * t16][nl], s[2 * t16 + 1][nl]);
            Wt[(bn * 32 + nl) * 64 + bk * 16 + t16] = pk;
        }
    } else {
        int e = (blockIdx.x - 32) * blockDim.x + threadIdx.x;
        if (e < E) atomicAdd(&cnt[dst[e]], 1);
    }
}

// ---- multi-block exclusive scan (fused dinv/y) ----

__global__ __launch_bounds__(SCAN_BLK) void scan_phase1(const int* __restrict__ cnt,
                                                        const float* __restrict__ x,
                                                        int* __restrict__ row_ptr,
                                                        int* __restrict__ bsum,
                                                        float* __restrict__ dinv,
                                                        float2* __restrict__ y, int N) {
    __shared__ int sm[SCAN_BLK];
    int i = blockIdx.x * SCAN_BLK + threadIdx.x;
    int v = (i < N) ? cnt[i] : 0;
    if (i < N) {
        float dv = rsqrtf((float)v + 1.0f);
        dinv[i] = dv;
        float2 xv = ((const float2*)x)[i];
        y[i] = make_float2(xv.x * dv, xv.y * dv);
    }
    sm[threadIdx.x] = v;
    __syncthreads();
    for (int off = 1; off < SCAN_BLK; off <<= 1) {
        int t = (threadIdx.x >= (unsigned)off) ? sm[threadIdx.x - off] : 0;
        __syncthreads();
        sm[threadIdx.x] += t;
        __syncthreads();
    }
    if (i < N) row_ptr[i] = sm[threadIdx.x] - v;
    if (threadIdx.x == SCAN_BLK - 1) bsum[blockIdx.x] = sm[SCAN_BLK - 1];
}

__global__ __launch_bounds__(SCAN_BLK) void scan_phase2(int* __restrict__ bsum, int nb,
                                                        const int* __restrict__ batch, int N,
                                                        int* __restrict__ goff) {
    if (threadIdx.x <= NGRAPH) {
        int g = threadIdx.x;
        int lo = 0, hi = N;
        while (lo < hi) {
            int mid = (lo + hi) >> 1;
            if (batch[mid] < g) lo = mid + 1; else hi = mid;
        }
        goff[g] = lo;
    }
    __shared__ int sm[SCAN_BLK];
    int v = (threadIdx.x < (unsigned)nb) ? bsum[threadIdx.x] : 0;
    sm[threadIdx.x] = v;
    __syncthreads();
    for (int off = 1; off < SCAN_BLK; off <<= 1) {
        int t = (threadIdx.x >= (unsigned)off) ? sm[threadIdx.x - off] : 0;
        __syncthreads();
        sm[threadIdx.x] += t;
        __syncthreads();
    }
    if (threadIdx.x < (unsigned)nb) bsum[threadIdx.x] = sm[threadIdx.x] - v;
}

__global__ __launch_bounds__(SCAN_BLK) void scan_phase3(int* __restrict__ row_ptr,
                                                        const int* __restrict__ bsum,
                                                        int N, int E) {
    int i = blockIdx.x * SCAN_BLK + threadIdx.x;
    if (i < N) row_ptr[i] += bsum[blockIdx.x];
    if (i == 0) row_ptr[N] = E;
}

// reverse-fill using cnt itself (dead after scan)
__global__ void fill_kernel(const int* __restrict__ src, const int* __restrict__ dst, int E,
                            const int* __restrict__ row_ptr, int* __restrict__ cnt,
                            int* __restrict__ col) {
    int e = blockIdx.x * blockDim.x + threadIdx.x;
    if (e < E) {
        int d = dst[e];
        int p = row_ptr[d] + atomicSub(&cnt[d], 1) - 1;
        col[p] = src[e];
    }
}

// ---------------- layer 1 fused: z = agg(y) ; h1 = tanh(z @ W1 + b1) (bf16, quarter-major out) --------

__global__ __launch_bounds__(256) void agg_x_t1(const float2* __restrict__ y,
                                                const int* __restrict__ row_ptr,
                                                const int* __restrict__ col,
                                                const float* __restrict__ dinv,
                                                const float* __restrict__ W1,
                                                const float* __restrict__ b1,
                                                unsigned short* __restrict__ h, int N) {
    __shared__ float4 sW[64];     // W1[2][128]
    __shared__ float4 sb[32];     // b1[128]
    __shared__ float2 zs[256];
    if (threadIdx.x < 64) sW[threadIdx.x] = ((const float4*)W1)[threadIdx.x];
    if (threadIdx.x < 32) sb[threadIdx.x] = ((const float4*)b1)[threadIdx.x];

    int v = blockIdx.x * 256 + threadIdx.x;
    float2 zv = make_float2(0.f, 0.f);
    if (v < N) {
        int s = row_ptr[v], e = row_ptr[v + 1];
        float2 a0 = y[v];
        float2 a1 = make_float2(0.f, 0.f);
        float2 a2 = make_float2(0.f, 0.f);
        float2 a3 = make_float2(0.f, 0.f);
        int j = s;
        for (; j + 4 <= e; j += 4) {
            int u0 = col[j], u1 = col[j + 1], u2 = col[j + 2], u3 = col[j + 3];
            float2 v0 = y[u0], v1 = y[u1], v2 = y[u2], v3 = y[u3];
            a0.x += v0.x; a0.y += v0.y;
            a1.x += v1.x; a1.y += v1.y;
            a2.x += v2.x; a2.y += v2.y;
            a3.x += v3.x; a3.y += v3.y;
        }
        for (; j < e; ++j) {
            float2 vv = y[col[j]];
            a0.x += vv.x; a0.y += vv.y;
        }
        float dv = dinv[v];
        zv = make_float2(dv * (a0.x + a1.x + a2.x + a3.x),
                         dv * (a0.y + a1.y + a2.y + a3.y));
    }
    zs[threadIdx.x] = zv;
    __syncthreads();

    int q = threadIdx.x & 31;          // col quad (4 cols)
    int rsub = threadIdx.x >> 5;       // 0..7
    float4 w0 = sW[q];
    float4 w1 = sW[32 + q];
    float4 b = sb[q];
    size_t qoff = (size_t)(q >> 3) * N;  // quarter base (rows)
#pragma unroll 4
    for (int pass = 0; pass < 32; ++pass) {
        int local = pass * 8 + rsub;
        int row = blockIdx.x * 256 + local;
        if (row >= N) break;
        float2 z = zs[local];
        float ox = tanhf(fmaf(z.x, w0.x, fmaf(z.y, w1.x, b.x)));
        float oy = tanhf(fmaf(z.x, w0.y, fmaf(z.y, w1.y, b.y)));
        float oz = tanhf(fmaf(z.x, w0.z, fmaf(z.y, w1.z, b.z)));
        float ow = tanhf(fmaf(z.x, w0.w, fmaf(z.y, w1.w, b.w)));
        uint2 pk;
        pk.x = pack_bf16x2(ox, oy);
        pk.y = pack_bf16x2(oz, ow);
        ((uint2*)h)[(qoff + row) * 8 + (q & 7)] = pk;
    }
}

// ---------------- MFMA GEMM: t[4][N][32](bf16) = (A[4][N][32](bf16) @ W) * dinv ----------------

__global__ __launch_bounds__(256) void gemm_mfma(const unsigned short* __restrict__ A,
                                                 const unsigned* __restrict__ Wt,
                                                 const float* __restrict__ dinv,
                                                 unsigned short* __restrict__ t, int N) {
    __shared__ unsigned sW[128 * 68];
    const uint4* Wt4 = (const uint4*)Wt;
    for (int i = threadIdx.x; i < 2048; i += 256) {
        int n = i >> 4, c = i & 15;
        *(uint4*)&sW[n * 68 + c * 4] = Wt4[i];
    }
    __syncthreads();
    int w = threadIdx.x >> 6;
    int l = threadIdx.x & 63;
    int lm = l & 15;
    int q4 = l >> 4;
    int k8 = q4 * 8;

    floatx4 acc[2][8];
#pragma unroll
    for (int i = 0; i < 2; ++i)
#pragma unroll
        for (int j = 0; j < 8; ++j) acc[i][j] = (floatx4){0.f, 0.f, 0.f, 0.f};

    int rowbase = blockIdx.x * 128 + w * 32;
#pragma unroll
    for (int ks = 0; ks < 4; ++ks) {
        // A element [r][ks*32 + k8 ..] lives in quarter ks at offset k8
        short8 a[2];
#pragma unroll
        for (int mt = 0; mt < 2; ++mt) {
            int r = min(rowbase + mt * 16 + lm, N - 1);
            a[mt] = *(const short8*)(A + ((size_t)ks * N + r) * 32 + k8);
        }
#pragma unroll
        for (int nt = 0; nt < 8; ++nt) {
            short8 b = *(const short8*)&sW[(nt * 16 + lm) * 68 + ks * 16 + q4 * 4];
#pragma unroll
            for (int mt = 0; mt < 2; ++mt)
                acc[mt][nt] = __builtin_amdgcn_mfma_f32_16x16x32_bf16(a[mt], b, acc[mt][nt], 0, 0, 0);
        }
    }

#pragma unroll
    for (int mt = 0; mt < 2; ++mt) {
#pragma unroll
        for (int reg = 0; reg < 4; ++reg) {
            int gr = rowbase + mt * 16 + q4 * 4 + reg;
            if (gr >= N) continue;
            float dv = dinv[gr];
#pragma unroll
            for (int nt = 0; nt < 8; ++nt) {
                // col c = nt*16+lm -> quarter nt>>1, offset (nt&1)*16+lm
                t[((size_t)(nt >> 1) * N + gr) * 32 + (nt & 1) * 16 + lm] =
                    bf16_1(acc[mt][nt][reg] * dv);
            }
        }
    }
}

// ---------------- aggregation: 16 nodes per wave, 4 lanes per node, one quarter per blockIdx.y -------
// No cross-lane reduce: lane (grp,q) privately accumulates its node's 8 bf16 cols over the
// node's edge list (4-unrolled independent gathers). Epilogue runs with all 64 lanes dense.
// Gather table per quarter = 3.2 MB -> XCD-L2 resident (x-fastest dispatch = one quarter at a time).

__global__ __launch_bounds__(256) void agg_kernel(const unsigned short* __restrict__ t,
                                                  const int* __restrict__ row_ptr,
                                                  const int* __restrict__ col,
                                                  const float* __restrict__ dinv,
                                                  const float* __restrict__ bias,
                                                  unsigned short* __restrict__ out, int N) {
    int lane = threadIdx.x & 63;
    int wave = threadIdx.x >> 6;
    int grp = lane >> 2;               // node slot 0..15
    int q = lane & 3;                  // 16B col slot (8 bf16)
    int qt = blockIdx.y;               // feature quarter 0..3
    int node = blockIdx.x * 64 + wave * 16 + grp;
    if (node >= N) return;
    const uint4* t4 = (const uint4*)t;
    unsigned qb = (unsigned)qt * (unsigned)N;
    int s = row_ptr[node];
    int deg = row_ptr[node + 1] - s;

    float a[8];
    {   // self term
        uint4 v = t4[(size_t)((qb + (unsigned)node) * 4u + q)];
        a[0] = bf16lo(v.x); a[1] = bf16hi(v.x);
        a[2] = bf16lo(v.y); a[3] = bf16hi(v.y);
        a[4] = bf16lo(v.z); a[5] = bf16hi(v.z);
        a[6] = bf16lo(v.w); a[7] = bf16hi(v.w);
    }
    int j = 0;
    for (; j + 4 <= deg; j += 4) {     // 4 independent gathers in flight
        int u0 = col[s + j];
        int u1 = col[s + j + 1];
        int u2 = col[s + j + 2];
        int u3 = col[s + j + 3];
        uint4 v0 = t4[(size_t)((qb + (unsigned)u0) * 4u + q)];
        uint4 v1 = t4[(size_t)((qb + (unsigned)u1) * 4u + q)];
        uint4 v2 = t4[(size_t)((qb + (unsigned)u2) * 4u + q)];
        uint4 v3 = t4[(size_t)((qb + (unsigned)u3) * 4u + q)];
        a[0] += bf16lo(v0.x); a[1] += bf16hi(v0.x);
        a[2] += bf16lo(v0.y); a[3] += bf16hi(v0.y);
        a[4] += bf16lo(v0.z); a[5] += bf16hi(v0.z);
        a[6] += bf16lo(v0.w); a[7] += bf16hi(v0.w);
        a[0] += bf16lo(v1.x); a[1] += bf16hi(v1.x);
        a[2] += bf16lo(v1.y); a[3] += bf16hi(v1.y);
        a[4] += bf16lo(v1.z); a[5] += bf16hi(v1.z);
        a[6] += bf16lo(v1.w); a[7] += bf16hi(v1.w);
        a[0] += bf16lo(v2.x); a[1] += bf16hi(v2.x);
        a[2] += bf16lo(v2.y); a[3] += bf16hi(v2.y);
        a[4] += bf16lo(v2.z); a[5] += bf16hi(v2.z);
        a[6] += bf16lo(v2.w); a[7] += bf16hi(v2.w);
        a[0] += bf16lo(v3.x); a[1] += bf16hi(v3.x);
        a[2] += bf16lo(v3.y); a[3] += bf16hi(v3.y);
        a[4] += bf16lo(v3.z); a[5] += bf16hi(v3.z);
        a[6] += bf16lo(v3.w); a[7] += bf16hi(v3.w);
    }
    for (; j < deg; ++j) {
        int u = col[s + j];
        uint4 v = t4[(size_t)((qb + (unsigned)u) * 4u + q)];
        a[0] += bf16lo(v.x); a[1] += bf16hi(v.x);
        a[2] += bf16lo(v.y); a[3] += bf16hi(v.y);
        a[4] += bf16lo(v.z); a[5] += bf16hi(v.z);
        a[6] += bf16lo(v.w); a[7] += bf16hi(v.w);
    }

    float dv = dinv[node];
    const float4* b4 = (const float4*)bias;
    float4 b0 = b4[qt * 8 + q * 2];
    float4 b1 = b4[qt * 8 + q * 2 + 1];
    uint4 pk;
    pk.x = pack_bf16x2(tanhf(fmaf(dv, a[0], b0.x)), tanhf(fmaf(dv, a[1], b0.y)));
    pk.y = pack_bf16x2(tanhf(fmaf(dv, a[2], b0.z)), tanhf(fmaf(dv, a[3], b0.w)));
    pk.z = pack_bf16x2(tanhf(fmaf(dv, a[4], b1.x)), tanhf(fmaf(dv, a[5], b1.y)));
    pk.w = pack_bf16x2(tanhf(fmaf(dv, a[6], b1.z)), tanhf(fmaf(dv, a[7], b1.w)));
    ((uint4*)out)[(size_t)((qb + (unsigned)node) * 4u + q)] = pk;
}

// ---------------- pooling (bf16 h, quarter-major) + fused output head ----------------

__global__ __launch_bounds__(128) void pool_partial(const unsigned short* __restrict__ h,
                                                    const int* __restrict__ goff,
                                                    float* __restrict__ part, int N) {
    int g = blockIdx.x;
    int c = blockIdx.y;
    int j = threadIdx.x;
    int s = goff[g], e = goff[g + 1];
    int cnt = e - s;
    int per = (cnt + POOL_CHUNKS - 1) / POOL_CHUNKS;
    int ps = s + c * per;
    int pe = min(ps + per, e);
    size_t qoff = (size_t)(j >> 5) * N;
    int jq = j & 31;
    float mx = -3.402823466e+38f, sm = 0.f;
    for (int n = ps; n < pe; ++n) {
        float v = __uint_as_float(((unsigned)h[(qoff + n) * 32 + jq]) << 16);
        mx = fmaxf(mx, v);
        sm += v;
    }
    float* dst = part + ((size_t)g * POOL_CHUNKS + c) * 256;
    dst[j] = mx;
    dst[128 + j] = sm;
}

__global__ __launch_bounds__(128) void pool_final(const float* __restrict__ part,
                                                  const int* __restrict__ goff,
                                                  const float* __restrict__ Wo,
                                                  const float* __restrict__ bo,
                                                  float* __restrict__ out) {
    __shared__ float p[256];
    int g = blockIdx.x;
    int j = threadIdx.x;
    float mx = -3.402823466e+38f, sm = 0.f;
    const float* base = part + (size_t)g * POOL_CHUNKS * 256;
#pragma unroll 4
    for (int c = 0; c < POOL_CHUNKS; ++c) {
        mx = fmaxf(mx, base[c * 256 + j]);
        sm += base[c * 256 + 128 + j];
    }
    int cnt = goff[g + 1] - goff[g];
    p[j] = (cnt > 0) ? mx : 0.f;
    p[128 + j] = sm / fmaxf((float)cnt, 1.f);
    __syncthreads();
    if (j < 41) {
        float acc = bo[j];
        for (int k = 0; k < 256; ++k) acc = fmaf(p[k], Wo[k * 41 + j], acc);
        out[g * 41 + j] = tanhf(acc);
    }
}

// ---------------- launch ----------------

extern "C" void kernel_launch(void* const* d_in, const int* in_sizes, int n_in,
                              void* d_out, int out_size, void* d_ws, size_t ws_size,
                              hipStream_t stream) {
    const float* x   = (const float*)d_in[0];
    const int*   ei  = (const int*)d_in[1];
    const int* batch = (const int*)d_in[2];
    const float* W1  = (const float*)d_in[3];
    const float* b1  = (const float*)d_in[4];
    const float* W2  = (const float*)d_in[5];
    const float* b2  = (const float*)d_in[6];
    const float* W3  = (const float*)d_in[7];
    const float* b3  = (const float*)d_in[8];
    const float* Wo  = (const float*)d_in[9];
    const float* bo  = (const float*)d_in[10];
    float* outp = (float*)d_out;

    int N = in_sizes[2];
    int E = in_sizes[1] / 2;
    const int* src = ei;
    const int* dst = ei + E;

    char* p = (char*)d_ws;
    auto alloc = [&](size_t bytes) -> char* {
        char* q = p;
        p += (bytes + 255) & ~(size_t)255;
        return q;
    };
    unsigned short* t   = (unsigned short*)alloc((size_t)N * 128 * 2);  // bf16 gemm out [4][N][32]
    unsigned short* hb  = (unsigned short*)alloc((size_t)N * 128 * 2);  // bf16 h1 / h2  [4][N][32]
    unsigned short* h3b = (unsigned short*)alloc((size_t)N * 128 * 2);  // bf16 h3       [4][N][32]
    float* dinv   = (float*)alloc((size_t)N * 4);
    int*   cnt    = (int*)alloc((size_t)N * 4);
    int*   rowp   = (int*)alloc((size_t)(N + 1) * 4);
    int*   col    = (int*)alloc((size_t)E * 4);
    int*   goff   = (int*)alloc(65 * 4);
    float* part   = (float*)alloc((size_t)NGRAPH * POOL_CHUNKS * 256 * 4);
    float2* y     = (float2*)alloc((size_t)N * 8);
    unsigned* Wt2 = (unsigned*)alloc(128 * 64 * 4);
    unsigned* Wt3 = (unsigned*)alloc(128 * 64 * 4);
    int nscan = (N + SCAN_BLK - 1) / SCAN_BLK;
    int*   bsum   = (int*)alloc((size_t)nscan * 4);

    hipMemsetAsync(cnt, 0, (size_t)N * 4, stream);

    pack_count<<<32 + (E + 255) / 256, 256, 0, stream>>>(dst, E, cnt, W2, W3, Wt2, Wt3);
    scan_phase1<<<nscan, SCAN_BLK, 0, stream>>>(cnt, x, rowp, bsum, dinv, y, N);
    scan_phase2<<<1, SCAN_BLK, 0, stream>>>(bsum, nscan, batch, N, goff);
    scan_phase3<<<nscan, SCAN_BLK, 0, stream>>>(rowp, bsum, N, E);
    fill_kernel<<<(E + 255) / 256, 256, 0, stream>>>(src, dst, E, rowp, cnt, col);

    dim3 agrid((N + 63) / 64, 4);  // x = node blocks (fast), y = feature quarter (slow)

    // layer 1: fused agg(x) + transform -> h1 (bf16, quarter-major)
    agg_x_t1<<<(N + 255) / 256, 256, 0, stream>>>(y, rowp, col, dinv, W1, b1, hb, N);
    // layer 2
    gemm_mfma<<<(N + 127) / 128, 256, 0, stream>>>(hb, Wt2, dinv, t, N);
    agg_kernel<<<agrid, 256, 0, stream>>>(t, rowp, col, dinv, b2, hb, N);
    // layer 3
    gemm_mfma<<<(N + 127) / 128, 256, 0, stream>>>(hb, Wt3, dinv, t, N);
    agg_kernel<<<agrid, 256, 0, stream>>>(t, rowp, col, dinv, b3, h3b, N);

    // pool + fused head
    dim3 pgrid(NGRAPH, POOL_CHUNKS);
    pool_partial<<<pgrid, 128, 0, stream>>>(h3b, goff, part, N);
    pool_final<<<NGRAPH, 128, 0, stream>>>(part, goff, Wo, bo, outp);
}

// Round 4
// 274.590 us; speedup vs baseline: 1.3250x; 1.0121x over previous
//
#include <hip/hip_runtime.h>
#include <math.h>

#define NGRAPH 64
#define SCAN_BLK 1024

typedef short short8 __attribute__((ext_vector_type(8)));
typedef float floatx4 __attribute__((ext_vector_type(4)));

__device__ inline unsigned pack_bf16x2(float a, float b) {
    unsigned ua = __float_as_uint(a);
    unsigned ub = __float_as_uint(b);
    ua = (ua + 0x7fffu + ((ua >> 16) & 1u)) >> 16;   // RNE
    ub = (ub + 0x7fffu + ((ub >> 16) & 1u)) >> 16;
    return ua | (ub << 16);
}
__device__ inline unsigned short bf16_1(float a) {
    unsigned ua = __float_as_uint(a);
    return (unsigned short)((ua + 0x7fffu + ((ua >> 16) & 1u)) >> 16);
}
__device__ inline float bf16lo(unsigned u) { return __uint_as_float(u << 16); }
__device__ inline float bf16hi(unsigned u) { return __uint_as_float(u & 0xffff0000u); }

// order-preserving float->uint key (monotone); uint 0 is below every real key -> memset-0 identity
__device__ inline unsigned fkey(float v) {
    unsigned u = __float_as_uint(v);
    return (v >= 0.f) ? (u | 0x80000000u) : ~u;
}

// All 128-wide bf16 intermediates use QUARTER-MAJOR layout: [4][N][32] bf16.
// Quarter q of node n lives at ((size_t)q * N + n) * 32 .. +31 (3.2 MB -> XCD-L2 resident).

// ---------------- fused: W2/W3 transpose+bf16-pack (blocks 0..31) + degree count (rest) ----------------

__global__ void pack_count(const int* __restrict__ dst, int E, int* __restrict__ cnt,
                           const float* __restrict__ W2, const float* __restrict__ W3,
                           unsigned* __restrict__ Wt2, unsigned* __restrict__ Wt3) {
    if (blockIdx.x < 32) {
        int b = blockIdx.x;
        const float* W = (b < 16) ? W2 : W3;
        unsigned* Wt = (b < 16) ? Wt2 : Wt3;
        b &= 15;
        int bk = b & 3, bn = b >> 2;
        __shared__ float s[32][33];
        int tx = threadIdx.x & 31, ty = threadIdx.x >> 5;
#pragma unroll
        for (int r = 0; r < 4; ++r)
            s[r * 8 + ty][tx] = W[(bk * 32 + r * 8 + ty) * 128 + bn * 32 + tx];
        __syncthreads();
        int t16 = threadIdx.x & 15, tn = threadIdx.x >> 4;
#pragma unroll
        for (int pass = 0; pass < 2; ++pass) {
            int nl = pass * 16 + tn;
            unsigned pk = pack_bf16x2(s[2 * t16][nl], s[2 * t16 + 1][nl]);
            Wt[(bn * 32 + nl) * 64 + bk * 16 + t16] = pk;
        }
    } else {
        int e = (blockIdx.x - 32) * blockDim.x + threadIdx.x;
        if (e < E) atomicAdd(&cnt[dst[e]], 1);
    }
}

// ---- fused scan: per-block exclusive scan + last-block closes (block-offset scan + goff) ----
// Consumers compute final row_ptr as row_ptr[i] + bsum[i>>10] on the fly.

__global__ __launch_bounds__(SCAN_BLK) void scanA(const int* __restrict__ cnt,
                                                  const float* __restrict__ x,
                                                  int* __restrict__ row_ptr,
                                                  int* __restrict__ bsum,
                                                  float* __restrict__ dinv,
                                                  float2* __restrict__ y,
                                                  const int* __restrict__ batch,
                                                  int* __restrict__ ticket,
                                                  int* __restrict__ goff, int N) {
    __shared__ int sm[SCAN_BLK];
    __shared__ int amLast;
    int i = blockIdx.x * SCAN_BLK + threadIdx.x;
    int v = (i < N) ? cnt[i] : 0;
    if (i < N) {
        float dv = rsqrtf((float)v + 1.0f);
        dinv[i] = dv;
        float2 xv = ((const float2*)x)[i];
        y[i] = make_float2(xv.x * dv, xv.y * dv);
    }
    sm[threadIdx.x] = v;
    __syncthreads();
    for (int off = 1; off < SCAN_BLK; off <<= 1) {
        int t = (threadIdx.x >= (unsigned)off) ? sm[threadIdx.x - off] : 0;
        __syncthreads();
        sm[threadIdx.x] += t;
        __syncthreads();
    }
    if (i < N) row_ptr[i] = sm[threadIdx.x] - v;
    if (threadIdx.x == SCAN_BLK - 1) bsum[blockIdx.x] = sm[SCAN_BLK - 1];
    __syncthreads();                       // all block stores issued & drained
    if (threadIdx.x == 0) {
        __threadfence();                   // publish this block's stores device-wide
        amLast = (atomicAdd(ticket, 1) == (int)gridDim.x - 1);
    }
    __syncthreads();
    if (!amLast) return;
    // closer block: exclusive-scan the block sums (coherent atomic reads), compute goff
    int nb = (int)gridDim.x;
    int v2 = (threadIdx.x < (unsigned)nb) ? atomicAdd(&bsum[threadIdx.x], 0) : 0;
    sm[threadIdx.x] = v2;
    __syncthreads();
    for (int off = 1; off < SCAN_BLK; off <<= 1) {
        int t = (threadIdx.x >= (unsigned)off) ? sm[threadIdx.x - off] : 0;
        __syncthreads();
        sm[threadIdx.x] += t;
        __syncthreads();
    }
    if (threadIdx.x < (unsigned)nb) bsum[threadIdx.x] = sm[threadIdx.x] - v2;
    if (threadIdx.x <= NGRAPH) {
        int g = threadIdx.x;
        int lo = 0, hi = N;
        while (lo < hi) {
            int mid = (lo + hi) >> 1;
            if (batch[mid] < g) lo = mid + 1; else hi = mid;
        }
        goff[g] = lo;
    }
}

// reverse-fill using cnt itself (dead after scan); applies block offset on the fly
__global__ void fill_kernel(const int* __restrict__ src, const int* __restrict__ dst, int E,
                            const int* __restrict__ row_ptr, const int* __restrict__ bsum,
                            int* __restrict__ cnt, int* __restrict__ col) {
    int e = blockIdx.x * blockDim.x + threadIdx.x;
    if (e < E) {
        int d = dst[e];
        int base = row_ptr[d] + bsum[d >> 10];
        int p = base + atomicSub(&cnt[d], 1) - 1;
        col[p] = src[e];
    }
}

// ---------------- layer 1 fused: z = agg(y) ; h1 = tanh(z @ W1 + b1) (bf16, quarter-major out) --------

__global__ __launch_bounds__(256) void agg_x_t1(const float2* __restrict__ y,
                                                const int* __restrict__ row_ptr,
                                                const int* __restrict__ bsum,
                                                const int* __restrict__ col,
                                                const float* __restrict__ dinv,
                                                const float* __restrict__ W1,
                                                const float* __restrict__ b1,
                                                unsigned short* __restrict__ h, int N, int E) {
    __shared__ float4 sW[64];     // W1[2][128]
    __shared__ float4 sb[32];     // b1[128]
    __shared__ float2 zs[256];
    if (threadIdx.x < 64) sW[threadIdx.x] = ((const float4*)W1)[threadIdx.x];
    if (threadIdx.x < 32) sb[threadIdx.x] = ((const float4*)b1)[threadIdx.x];

    int v = blockIdx.x * 256 + threadIdx.x;
    float2 zv = make_float2(0.f, 0.f);
    if (v < N) {
        int s = row_ptr[v] + bsum[v >> 10];
        int e = (v + 1 < N) ? row_ptr[v + 1] + bsum[(v + 1) >> 10] : E;
        float2 a0 = y[v];
        float2 a1 = make_float2(0.f, 0.f);
        float2 a2 = make_float2(0.f, 0.f);
        float2 a3 = make_float2(0.f, 0.f);
        int j = s;
        for (; j + 4 <= e; j += 4) {
            int u0 = col[j], u1 = col[j + 1], u2 = col[j + 2], u3 = col[j + 3];
            float2 v0 = y[u0], v1 = y[u1], v2 = y[u2], v3 = y[u3];
            a0.x += v0.x; a0.y += v0.y;
            a1.x += v1.x; a1.y += v1.y;
            a2.x += v2.x; a2.y += v2.y;
            a3.x += v3.x; a3.y += v3.y;
        }
        for (; j < e; ++j) {
            float2 vv = y[col[j]];
            a0.x += vv.x; a0.y += vv.y;
        }
        float dv = dinv[v];
        zv = make_float2(dv * (a0.x + a1.x + a2.x + a3.x),
                         dv * (a0.y + a1.y + a2.y + a3.y));
    }
    zs[threadIdx.x] = zv;
    __syncthreads();

    int q = threadIdx.x & 31;          // col quad (4 cols)
    int rsub = threadIdx.x >> 5;       // 0..7
    float4 w0 = sW[q];
    float4 w1 = sW[32 + q];
    float4 b = sb[q];
    size_t qoff = (size_t)(q >> 3) * N;  // quarter base (rows)
#pragma unroll 4
    for (int pass = 0; pass < 32; ++pass) {
        int local = pass * 8 + rsub;
        int row = blockIdx.x * 256 + local;
        if (row >= N) break;
        float2 z = zs[local];
        float ox = tanhf(fmaf(z.x, w0.x, fmaf(z.y, w1.x, b.x)));
        float oy = tanhf(fmaf(z.x, w0.y, fmaf(z.y, w1.y, b.y)));
        float oz = tanhf(fmaf(z.x, w0.z, fmaf(z.y, w1.z, b.z)));
        float ow = tanhf(fmaf(z.x, w0.w, fmaf(z.y, w1.w, b.w)));
        uint2 pk;
        pk.x = pack_bf16x2(ox, oy);
        pk.y = pack_bf16x2(oz, ow);
        ((uint2*)h)[(qoff + row) * 8 + (q & 7)] = pk;
    }
}

// ---------------- MFMA GEMM: t[4][N][32](bf16) = (A[4][N][32](bf16) @ W) * dinv ----------------

__global__ __launch_bounds__(256) void gemm_mfma(const unsigned short* __restrict__ A,
                                                 const unsigned* __restrict__ Wt,
                                                 const float* __restrict__ dinv,
                                                 unsigned short* __restrict__ t, int N) {
    __shared__ unsigned sW[128 * 68];
    const uint4* Wt4 = (const uint4*)Wt;
    for (int i = threadIdx.x; i < 2048; i += 256) {
        int n = i >> 4, c = i & 15;
        *(uint4*)&sW[n * 68 + c * 4] = Wt4[i];
    }
    __syncthreads();
    int w = threadIdx.x >> 6;
    int l = threadIdx.x & 63;
    int lm = l & 15;
    int q4 = l >> 4;
    int k8 = q4 * 8;

    floatx4 acc[2][8];
#pragma unroll
    for (int i = 0; i < 2; ++i)
#pragma unroll
        for (int j = 0; j < 8; ++j) acc[i][j] = (floatx4){0.f, 0.f, 0.f, 0.f};

    int rowbase = blockIdx.x * 128 + w * 32;
#pragma unroll
    for (int ks = 0; ks < 4; ++ks) {
        short8 a[2];
#pragma unroll
        for (int mt = 0; mt < 2; ++mt) {
            int r = min(rowbase + mt * 16 + lm, N - 1);
            a[mt] = *(const short8*)(A + ((size_t)ks * N + r) * 32 + k8);
        }
#pragma unroll
        for (int nt = 0; nt < 8; ++nt) {
            short8 b = *(const short8*)&sW[(nt * 16 + lm) * 68 + ks * 16 + q4 * 4];
#pragma unroll
            for (int mt = 0; mt < 2; ++mt)
                acc[mt][nt] = __builtin_amdgcn_mfma_f32_16x16x32_bf16(a[mt], b, acc[mt][nt], 0, 0, 0);
        }
    }

#pragma unroll
    for (int mt = 0; mt < 2; ++mt) {
#pragma unroll
        for (int reg = 0; reg < 4; ++reg) {
            int gr = rowbase + mt * 16 + q4 * 4 + reg;
            if (gr >= N) continue;
            float dv = dinv[gr];
#pragma unroll
            for (int nt = 0; nt < 8; ++nt) {
                t[((size_t)(nt >> 1) * N + gr) * 32 + (nt & 1) * 16 + lm] =
                    bf16_1(acc[mt][nt][reg] * dv);
            }
        }
    }
}

// ---------------- layer-2 aggregation: 256 nodes/block (1024 thr), 4 lanes/node, quarter = blockIdx.y --

__global__ __launch_bounds__(1024) void agg_kernel(const unsigned short* __restrict__ t,
                                                   const int* __restrict__ row_ptr,
                                                   const int* __restrict__ bsum,
                                                   const int* __restrict__ col,
                                                   const float* __restrict__ dinv,
                                                   const float* __restrict__ bias,
                                                   unsigned short* __restrict__ out, int N, int E) {
    int q = threadIdx.x & 3;                       // 16B col slot (8 bf16)
    int node = blockIdx.x * 256 + (threadIdx.x >> 2);
    int qt = blockIdx.y;                           // feature quarter 0..3
    if (node >= N) return;
    const uint4* t4 = (const uint4*)t;
    unsigned qb = (unsigned)qt * (unsigned)N;
    int s = row_ptr[node] + bsum[node >> 10];
    int e = (node + 1 < N) ? row_ptr[node + 1] + bsum[(node + 1) >> 10] : E;
    int deg = e - s;

    float a[8];
    {   // self term
        uint4 v = t4[(size_t)((qb + (unsigned)node) * 4u + q)];
        a[0] = bf16lo(v.x); a[1] = bf16hi(v.x);
        a[2] = bf16lo(v.y); a[3] = bf16hi(v.y);
        a[4] = bf16lo(v.z); a[5] = bf16hi(v.z);
        a[6] = bf16lo(v.w); a[7] = bf16hi(v.w);
    }
    int j = 0;
    for (; j + 4 <= deg; j += 4) {
        int u0 = col[s + j];
        int u1 = col[s + j + 1];
        int u2 = col[s + j + 2];
        int u3 = col[s + j + 3];
        uint4 v0 = t4[(size_t)((qb + (unsigned)u0) * 4u + q)];
        uint4 v1 = t4[(size_t)((qb + (unsigned)u1) * 4u + q)];
        uint4 v2 = t4[(size_t)((qb + (unsigned)u2) * 4u + q)];
        uint4 v3 = t4[(size_t)((qb + (unsigned)u3) * 4u + q)];
        a[0] += bf16lo(v0.x); a[1] += bf16hi(v0.x);
        a[2] += bf16lo(v0.y); a[3] += bf16hi(v0.y);
        a[4] += bf16lo(v0.z); a[5] += bf16hi(v0.z);
        a[6] += bf16lo(v0.w); a[7] += bf16hi(v0.w);
        a[0] += bf16lo(v1.x); a[1] += bf16hi(v1.x);
        a[2] += bf16lo(v1.y); a[3] += bf16hi(v1.y);
        a[4] += bf16lo(v1.z); a[5] += bf16hi(v1.z);
        a[6] += bf16lo(v1.w); a[7] += bf16hi(v1.w);
        a[0] += bf16lo(v2.x); a[1] += bf16hi(v2.x);
        a[2] += bf16lo(v2.y); a[3] += bf16hi(v2.y);
        a[4] += bf16lo(v2.z); a[5] += bf16hi(v2.z);
        a[6] += bf16lo(v2.w); a[7] += bf16hi(v2.w);
        a[0] += bf16lo(v3.x); a[1] += bf16hi(v3.x);
        a[2] += bf16lo(v3.y); a[3] += bf16hi(v3.y);
        a[4] += bf16lo(v3.z); a[5] += bf16hi(v3.z);
        a[6] += bf16lo(v3.w); a[7] += bf16hi(v3.w);
    }
    for (; j < deg; ++j) {
        int u = col[s + j];
        uint4 v = t4[(size_t)((qb + (unsigned)u) * 4u + q)];
        a[0] += bf16lo(v.x); a[1] += bf16hi(v.x);
        a[2] += bf16lo(v.y); a[3] += bf16hi(v.y);
        a[4] += bf16lo(v.z); a[5] += bf16hi(v.z);
        a[6] += bf16lo(v.w); a[7] += bf16hi(v.w);
    }

    float dv = dinv[node];
    const float4* b4 = (const float4*)bias;
    float4 b0 = b4[qt * 8 + q * 2];
    float4 b1 = b4[qt * 8 + q * 2 + 1];
    uint4 pk;
    pk.x = pack_bf16x2(tanhf(fmaf(dv, a[0], b0.x)), tanhf(fmaf(dv, a[1], b0.y)));
    pk.y = pack_bf16x2(tanhf(fmaf(dv, a[2], b0.z)), tanhf(fmaf(dv, a[3], b0.w)));
    pk.z = pack_bf16x2(tanhf(fmaf(dv, a[4], b1.x)), tanhf(fmaf(dv, a[5], b1.y)));
    pk.w = pack_bf16x2(tanhf(fmaf(dv, a[6], b1.z)), tanhf(fmaf(dv, a[7], b1.w)));
    ((uint4*)out)[(size_t)((qb + (unsigned)node) * 4u + q)] = pk;
}

// ---------------- layer-3 aggregation + FUSED pooling (h3 never materialized) ----------------
// Per node: compute fp32 tanh outputs in-register; wave-butterfly max/sum when the wave's 16
// nodes share a graph (batch sorted), merge via LDS, then 128 global atomics per block.

__global__ __launch_bounds__(1024) void agg3_pool(const unsigned short* __restrict__ t,
                                                  const int* __restrict__ row_ptr,
                                                  const int* __restrict__ bsum,
                                                  const int* __restrict__ col,
                                                  const float* __restrict__ dinv,
                                                  const float* __restrict__ bias,
                                                  const int* __restrict__ batch,
                                                  unsigned* __restrict__ pmax,
                                                  float* __restrict__ psum, int N, int E) {
    __shared__ unsigned smax[2][32];
    __shared__ float ssum[2][32];
    if (threadIdx.x < 64) {
        smax[threadIdx.x >> 5][threadIdx.x & 31] = 0u;
        ssum[threadIdx.x >> 5][threadIdx.x & 31] = 0.f;
    }
    __syncthreads();

    int q = threadIdx.x & 3;
    int blockBase = (int)blockIdx.x * 256;
    int node = blockBase + ((int)threadIdx.x >> 2);
    int qt = blockIdx.y;
    bool valid = node < N;
    int nc = valid ? node : N - 1;
    const uint4* t4 = (const uint4*)t;
    unsigned qb = (unsigned)qt * (unsigned)N;
    int s = row_ptr[nc] + bsum[nc >> 10];
    int e = (nc + 1 < N) ? row_ptr[nc + 1] + bsum[(nc + 1) >> 10] : E;
    int deg = valid ? (e - s) : 0;

    float a[8];
    {   // self term (of nc; discarded for invalid lanes)
        uint4 v = t4[(size_t)((qb + (unsigned)nc) * 4u + q)];
        a[0] = bf16lo(v.x); a[1] = bf16hi(v.x);
        a[2] = bf16lo(v.y); a[3] = bf16hi(v.y);
        a[4] = bf16lo(v.z); a[5] = bf16hi(v.z);
        a[6] = bf16lo(v.w); a[7] = bf16hi(v.w);
    }
    int j = 0;
    for (; j + 4 <= deg; j += 4) {
        int u0 = col[s + j];
        int u1 = col[s + j + 1];
        int u2 = col[s + j + 2];
        int u3 = col[s + j + 3];
        uint4 v0 = t4[(size_t)((qb + (unsigned)u0) * 4u + q)];
        uint4 v1 = t4[(size_t)((qb + (unsigned)u1) * 4u + q)];
        uint4 v2 = t4[(size_t)((qb + (unsigned)u2) * 4u + q)];
        uint4 v3 = t4[(size_t)((qb + (unsigned)u3) * 4u + q)];
        a[0] += bf16lo(v0.x); a[1] += bf16hi(v0.x);
        a[2] += bf16lo(v0.y); a[3] += bf16hi(v0.y);
        a[4] += bf16lo(v0.z); a[5] += bf16hi(v0.z);
        a[6] += bf16lo(v0.w); a[7] += bf16hi(v0.w);
        a[0] += bf16lo(v1.x); a[1] += bf16hi(v1.x);
        a[2] += bf16lo(v1.y); a[3] += bf16hi(v1.y);
        a[4] += bf16lo(v1.z); a[5] += bf16hi(v1.z);
        a[6] += bf16lo(v1.w); a[7] += bf16hi(v1.w);
        a[0] += bf16lo(v2.x); a[1] += bf16hi(v2.x);
        a[2] += bf16lo(v2.y); a[3] += bf16hi(v2.y);
        a[4] += bf16lo(v2.z); a[5] += bf16hi(v2.z);
        a[6] += bf16lo(v2.w); a[7] += bf16hi(v2.w);
        a[0] += bf16lo(v3.x); a[1] += bf16hi(v3.x);
        a[2] += bf16lo(v3.y); a[3] += bf16hi(v3.y);
        a[4] += bf16lo(v3.z); a[5] += bf16hi(v3.z);
        a[6] += bf16lo(v3.w); a[7] += bf16hi(v3.w);
    }
    for (; j < deg; ++j) {
        int u = col[s + j];
        uint4 v = t4[(size_t)((qb + (unsigned)u) * 4u + q)];
        a[0] += bf16lo(v.x); a[1] += bf16hi(v.x);
        a[2] += bf16lo(v.y); a[3] += bf16hi(v.y);
        a[4] += bf16lo(v.z); a[5] += bf16hi(v.z);
        a[6] += bf16lo(v.w); a[7] += bf16hi(v.w);
    }

    float dv = dinv[nc];
    const float4* b4 = (const float4*)bias;
    float4 b0 = b4[qt * 8 + q * 2];
    float4 b1 = b4[qt * 8 + q * 2 + 1];
    float o[8];
    o[0] = tanhf(fmaf(dv, a[0], b0.x)); o[1] = tanhf(fmaf(dv, a[1], b0.y));
    o[2] = tanhf(fmaf(dv, a[2], b0.z)); o[3] = tanhf(fmaf(dv, a[3], b0.w));
    o[4] = tanhf(fmaf(dv, a[4], b1.x)); o[5] = tanhf(fmaf(dv, a[5], b1.y));
    o[6] = tanhf(fmaf(dv, a[6], b1.z)); o[7] = tanhf(fmaf(dv, a[7], b1.w));

    int g = batch[nc];
    int g0 = batch[min(blockBase, N - 1)];
    int gl = __shfl(g, 0, 64);
    int gh = __shfl(g, 63, 64);

    if (gl == gh) {
        // fast path: whole wave in one graph -> butterfly reduce over the 16 node groups
        float m[8], sv[8];
#pragma unroll
        for (int k = 0; k < 8; ++k) {
            m[k] = valid ? o[k] : -3.402823466e+38f;
            sv[k] = valid ? o[k] : 0.f;
        }
#pragma unroll
        for (int st = 4; st < 64; st <<= 1) {
#pragma unroll
            for (int k = 0; k < 8; ++k) {
                m[k] = fmaxf(m[k], __shfl_xor(m[k], st, 64));
                sv[k] += __shfl_xor(sv[k], st, 64);
            }
        }
        if (((threadIdx.x & 63) >> 2) == 0) {   // 4 lanes (q=0..3) hold reduced values
            int seg = gl - g0;
            if (seg < 2) {
#pragma unroll
                for (int k = 0; k < 8; ++k) {
                    atomicMax(&smax[seg][q * 8 + k], fkey(m[k]));
                    atomicAdd(&ssum[seg][q * 8 + k], sv[k]);
                }
            } else {                            // safety net (tiny graphs)
#pragma unroll
                for (int k = 0; k < 8; ++k) {
                    atomicMax(&pmax[gl * 128 + qt * 32 + q * 8 + k], fkey(m[k]));
                    atomicAdd(&psum[gl * 128 + qt * 32 + q * 8 + k], sv[k]);
                }
            }
        }
    } else {
        // boundary wave: per-lane merge
        if (valid) {
            int seg = g - g0;
            if (seg < 2) {
#pragma unroll
                for (int k = 0; k < 8; ++k) {
                    atomicMax(&smax[seg][q * 8 + k], fkey(o[k]));
                    atomicAdd(&ssum[seg][q * 8 + k], o[k]);
                }
            } else {
#pragma unroll
                for (int k = 0; k < 8; ++k) {
                    atomicMax(&pmax[g * 128 + qt * 32 + q * 8 + k], fkey(o[k]));
                    atomicAdd(&psum[g * 128 + qt * 32 + q * 8 + k], o[k]);
                }
            }
        }
    }
    __syncthreads();
    if (threadIdx.x < 64) {
        int seg = threadIdx.x >> 5, c = threadIdx.x & 31;
        int g0b = batch[min(blockBase, N - 1)];
        int gg = g0b + seg;
        if (gg < NGRAPH) {
            atomicMax(&pmax[gg * 128 + qt * 32 + c], smax[seg][c]);
            atomicAdd(&psum[gg * 128 + qt * 32 + c], ssum[seg][c]);
        }
    }
}

// ---------------- final: decode pooled accumulators + output head ----------------

__global__ __launch_bounds__(128) void pool_final(const unsigned* __restrict__ pmax,
                                                  const float* __restrict__ psum,
                                                  const int* __restrict__ goff,
                                                  const float* __restrict__ Wo,
                                                  const float* __restrict__ bo,
                                                  float* __restrict__ out) {
    __shared__ float p[256];
    int g = blockIdx.x;
    int j = threadIdx.x;
    int cnt = goff[g + 1] - goff[g];
    unsigned key = pmax[g * 128 + j];
    float mx = (key & 0x80000000u) ? __uint_as_float(key ^ 0x80000000u)
                                   : __uint_as_float(~key);
    p[j] = (cnt > 0) ? mx : 0.f;
    p[128 + j] = psum[g * 128 + j] / fmaxf((float)cnt, 1.f);
    __syncthreads();
    if (j < 41) {
        float acc = bo[j];
        for (int k = 0; k < 256; ++k) acc = fmaf(p[k], Wo[k * 41 + j], acc);
        out[g * 41 + j] = tanhf(acc);
    }
}

// ---------------- launch ----------------

extern "C" void kernel_launch(void* const* d_in, const int* in_sizes, int n_in,
                              void* d_out, int out_size, void* d_ws, size_t ws_size,
                              hipStream_t stream) {
    const float* x   = (const float*)d_in[0];
    const int*   ei  = (const int*)d_in[1];
    const int* batch = (const int*)d_in[2];
    const float* W1  = (const float*)d_in[3];
    const float* b1  = (const float*)d_in[4];
    const float* W2  = (const float*)d_in[5];
    const float* b2  = (const float*)d_in[6];
    const float* W3  = (const float*)d_in[7];
    const float* b3  = (const float*)d_in[8];
    const float* Wo  = (const float*)d_in[9];
    const float* bo  = (const float*)d_in[10];
    float* outp = (float*)d_out;

    int N = in_sizes[2];
    int E = in_sizes[1] / 2;
    const int* src = ei;
    const int* dst = ei + E;

    char* p = (char*)d_ws;
    auto alloc = [&](size_t bytes) -> char* {
        char* q = p;
        p += (bytes + 255) & ~(size_t)255;
        return q;
    };
    unsigned short* t   = (unsigned short*)alloc((size_t)N * 128 * 2);  // bf16 gemm out [4][N][32]
    unsigned short* hb  = (unsigned short*)alloc((size_t)N * 128 * 2);  // bf16 h1 / h2  [4][N][32]
    float* dinv   = (float*)alloc((size_t)N * 4);
    int*   rowp   = (int*)alloc((size_t)(N + 1) * 4);
    int*   col    = (int*)alloc((size_t)E * 4);
    int*   goff   = (int*)alloc(65 * 4);
    float2* y     = (float2*)alloc((size_t)N * 8);
    unsigned* Wt2 = (unsigned*)alloc(128 * 64 * 4);
    unsigned* Wt3 = (unsigned*)alloc(128 * 64 * 4);
    int nscan = (N + SCAN_BLK - 1) / SCAN_BLK;
    int*   bsum   = (int*)alloc((size_t)nscan * 4);
    // zero-init region: cnt | ticket | pmax | psum (single memset)
    size_t cntB = ((size_t)N * 4 + 255) & ~(size_t)255;
    char* zbase = alloc(cntB + 256 + NGRAPH * 128 * 4 * 2);
    int*      cnt  = (int*)zbase;
    int*      tick = (int*)(zbase + cntB);
    unsigned* pmax = (unsigned*)(zbase + cntB + 256);
    float*    psum = (float*)(zbase + cntB + 256 + NGRAPH * 128 * 4);

    (void)hipMemsetAsync(zbase, 0, cntB + 256 + NGRAPH * 128 * 4 * 2, stream);

    pack_count<<<32 + (E + 255) / 256, 256, 0, stream>>>(dst, E, cnt, W2, W3, Wt2, Wt3);
    scanA<<<nscan, SCAN_BLK, 0, stream>>>(cnt, x, rowp, bsum, dinv, y, batch, tick, goff, N);
    fill_kernel<<<(E + 255) / 256, 256, 0, stream>>>(src, dst, E, rowp, bsum, cnt, col);

    dim3 agrid((N + 255) / 256, 4);  // x = node blocks (fast), y = feature quarter (slow)

    // layer 1: fused agg(x) + transform -> h1 (bf16, quarter-major)
    agg_x_t1<<<(N + 255) / 256, 256, 0, stream>>>(y, rowp, bsum, col, dinv, W1, b1, hb, N, E);
    // layer 2
    gemm_mfma<<<(N + 127) / 128, 256, 0, stream>>>(hb, Wt2, dinv, t, N);
    agg_kernel<<<agrid, 1024, 0, stream>>>(t, rowp, bsum, col, dinv, b2, hb, N, E);
    // layer 3 (pooling fused into agg)
    gemm_mfma<<<(N + 127) / 128, 256, 0, stream>>>(hb, Wt3, dinv, t, N);
    agg3_pool<<<agrid, 1024, 0, stream>>>(t, rowp, bsum, col, dinv, b3, batch, pmax, psum, N, E);

    pool_final<<<NGRAPH, 128, 0, stream>>>(pmax, psum, goff, Wo, bo, outp);
}

// Round 5
// 264.664 us; speedup vs baseline: 1.3747x; 1.0375x over previous
//
#include <hip/hip_runtime.h>
#include <math.h>

#define NGRAPH 64
#define SCAN_BLK 1024

typedef short short8 __attribute__((ext_vector_type(8)));
typedef float floatx4 __attribute__((ext_vector_type(4)));

__device__ inline unsigned pack_bf16x2(float a, float b) {
    unsigned ua = __float_as_uint(a);
    unsigned ub = __float_as_uint(b);
    ua = (ua + 0x7fffu + ((ua >> 16) & 1u)) >> 16;   // RNE
    ub = (ub + 0x7fffu + ((ub >> 16) & 1u)) >> 16;
    return ua | (ub << 16);
}
__device__ inline unsigned short bf16_1(float a) {
    unsigned ua = __float_as_uint(a);
    return (unsigned short)((ua + 0x7fffu + ((ua >> 16) & 1u)) >> 16);
}
__device__ inline float bf16lo(unsigned u) { return __uint_as_float(u << 16); }
__device__ inline float bf16hi(unsigned u) { return __uint_as_float(u & 0xffff0000u); }

// order-preserving float->uint key (monotone); uint 0 is below every real key -> memset-0 identity
__device__ inline unsigned fkey(float v) {
    unsigned u = __float_as_uint(v);
    return (v >= 0.f) ? (u | 0x80000000u) : ~u;
}

// All 128-wide bf16 intermediates use QUARTER-MAJOR layout: [4][N][32] bf16.
// Quarter q of node n lives at ((size_t)q * N + n) * 32 .. +31 (3.2 MB slice).
// Agg kernels use XCD-affinity swizzle: blocks land on XCD (bid%8); quarter = (bid%8)>>1,
// so each XCD pair owns ONE quarter -> 3.2 MB working set fits the XCD's 4 MB L2.

// ---------------- fused: W2/W3 transpose+bf16-pack (blocks 0..31) + degree count (rest) ----------------

__global__ void pack_count(const int* __restrict__ dst, int E, int* __restrict__ cnt,
                           const float* __restrict__ W2, const float* __restrict__ W3,
                           unsigned* __restrict__ Wt2, unsigned* __restrict__ Wt3) {
    if (blockIdx.x < 32) {
        int b = blockIdx.x;
        const float* W = (b < 16) ? W2 : W3;
        unsigned* Wt = (b < 16) ? Wt2 : Wt3;
        b &= 15;
        int bk = b & 3, bn = b >> 2;
        __shared__ float s[32][33];
        int tx = threadIdx.x & 31, ty = threadIdx.x >> 5;
#pragma unroll
        for (int r = 0; r < 4; ++r)
            s[r * 8 + ty][tx] = W[(bk * 32 + r * 8 + ty) * 128 + bn * 32 + tx];
        __syncthreads();
        int t16 = threadIdx.x & 15, tn = threadIdx.x >> 4;
#pragma unroll
        for (int pass = 0; pass < 2; ++pass) {
            int nl = pass * 16 + tn;
            unsigned pk = pack_bf16x2(s[2 * t16][nl], s[2 * t16 + 1][nl]);
            Wt[(bn * 32 + nl) * 64 + bk * 16 + t16] = pk;
        }
    } else {
        int e = (blockIdx.x - 32) * blockDim.x + threadIdx.x;
        if (e < E) atomicAdd(&cnt[dst[e]], 1);
    }
}

// ---- fused scan: per-block exclusive scan + last-block closes (block-offset scan + goff) ----
// Consumers compute final row_ptr as row_ptr[i] + bsum[i>>10] on the fly.

__global__ __launch_bounds__(SCAN_BLK) void scanA(const int* __restrict__ cnt,
                                                  const float* __restrict__ x,
                                                  int* __restrict__ row_ptr,
                                                  int* __restrict__ bsum,
                                                  float* __restrict__ dinv,
                                                  float2* __restrict__ y,
                                                  const int* __restrict__ batch,
                                                  int* __restrict__ ticket,
                                                  int* __restrict__ goff, int N) {
    __shared__ int sm[SCAN_BLK];
    __shared__ int amLast;
    int i = blockIdx.x * SCAN_BLK + threadIdx.x;
    int v = (i < N) ? cnt[i] : 0;
    if (i < N) {
        float dv = rsqrtf((float)v + 1.0f);
        dinv[i] = dv;
        float2 xv = ((const float2*)x)[i];
        y[i] = make_float2(xv.x * dv, xv.y * dv);
    }
    sm[threadIdx.x] = v;
    __syncthreads();
    for (int off = 1; off < SCAN_BLK; off <<= 1) {
        int t = (threadIdx.x >= (unsigned)off) ? sm[threadIdx.x - off] : 0;
        __syncthreads();
        sm[threadIdx.x] += t;
        __syncthreads();
    }
    if (i < N) row_ptr[i] = sm[threadIdx.x] - v;
    if (threadIdx.x == SCAN_BLK - 1) bsum[blockIdx.x] = sm[SCAN_BLK - 1];
    __syncthreads();                       // all block stores issued & drained
    if (threadIdx.x == 0) {
        __threadfence();                   // publish this block's stores device-wide
        amLast = (atomicAdd(ticket, 1) == (int)gridDim.x - 1);
    }
    __syncthreads();
    if (!amLast) return;
    // closer block: exclusive-scan the block sums (coherent atomic reads), compute goff
    int nb = (int)gridDim.x;
    int v2 = (threadIdx.x < (unsigned)nb) ? atomicAdd(&bsum[threadIdx.x], 0) : 0;
    sm[threadIdx.x] = v2;
    __syncthreads();
    for (int off = 1; off < SCAN_BLK; off <<= 1) {
        int t = (threadIdx.x >= (unsigned)off) ? sm[threadIdx.x - off] : 0;
        __syncthreads();
        sm[threadIdx.x] += t;
        __syncthreads();
    }
    if (threadIdx.x < (unsigned)nb) bsum[threadIdx.x] = sm[threadIdx.x] - v2;
    if (threadIdx.x <= NGRAPH) {
        int g = threadIdx.x;
        int lo = 0, hi = N;
        while (lo < hi) {
            int mid = (lo + hi) >> 1;
            if (batch[mid] < g) lo = mid + 1; else hi = mid;
        }
        goff[g] = lo;
    }
}

// reverse-fill using cnt itself (dead after scan); applies block offset on the fly
__global__ void fill_kernel(const int* __restrict__ src, const int* __restrict__ dst, int E,
                            const int* __restrict__ row_ptr, const int* __restrict__ bsum,
                            int* __restrict__ cnt, int* __restrict__ col) {
    int e = blockIdx.x * blockDim.x + threadIdx.x;
    if (e < E) {
        int d = dst[e];
        int base = row_ptr[d] + bsum[d >> 10];
        int p = base + atomicSub(&cnt[d], 1) - 1;
        col[p] = src[e];
    }
}

// ---------------- layer 1 fused: z = agg(y) ; h1 = tanh(z @ W1 + b1) (bf16, quarter-major out) --------

__global__ __launch_bounds__(256) void agg_x_t1(const float2* __restrict__ y,
                                                const int* __restrict__ row_ptr,
                                                const int* __restrict__ bsum,
                                                const int* __restrict__ col,
                                                const float* __restrict__ dinv,
                                                const float* __restrict__ W1,
                                                const float* __restrict__ b1,
                                                unsigned short* __restrict__ h, int N, int E) {
    __shared__ float4 sW[64];     // W1[2][128]
    __shared__ float4 sb[32];     // b1[128]
    __shared__ float2 zs[256];
    if (threadIdx.x < 64) sW[threadIdx.x] = ((const float4*)W1)[threadIdx.x];
    if (threadIdx.x < 32) sb[threadIdx.x] = ((const float4*)b1)[threadIdx.x];

    int v = blockIdx.x * 256 + threadIdx.x;
    float2 zv = make_float2(0.f, 0.f);
    if (v < N) {
        int s = row_ptr[v] + bsum[v >> 10];
        int e = (v + 1 < N) ? row_ptr[v + 1] + bsum[(v + 1) >> 10] : E;
        float2 a0 = y[v];
        float2 a1 = make_float2(0.f, 0.f);
        float2 a2 = make_float2(0.f, 0.f);
        float2 a3 = make_float2(0.f, 0.f);
        int j = s;
        for (; j + 4 <= e; j += 4) {
            int u0 = col[j], u1 = col[j + 1], u2 = col[j + 2], u3 = col[j + 3];
            float2 v0 = y[u0], v1 = y[u1], v2 = y[u2], v3 = y[u3];
            a0.x += v0.x; a0.y += v0.y;
            a1.x += v1.x; a1.y += v1.y;
            a2.x += v2.x; a2.y += v2.y;
            a3.x += v3.x; a3.y += v3.y;
        }
        for (; j < e; ++j) {
            float2 vv = y[col[j]];
            a0.x += vv.x; a0.y += vv.y;
        }
        float dv = dinv[v];
        zv = make_float2(dv * (a0.x + a1.x + a2.x + a3.x),
                         dv * (a0.y + a1.y + a2.y + a3.y));
    }
    zs[threadIdx.x] = zv;
    __syncthreads();

    int q = threadIdx.x & 31;          // col quad (4 cols)
    int rsub = threadIdx.x >> 5;       // 0..7
    float4 w0 = sW[q];
    float4 w1 = sW[32 + q];
    float4 b = sb[q];
    size_t qoff = (size_t)(q >> 3) * N;  // quarter base (rows)
#pragma unroll 4
    for (int pass = 0; pass < 32; ++pass) {
        int local = pass * 8 + rsub;
        int row = blockIdx.x * 256 + local;
        if (row >= N) break;
        float2 z = zs[local];
        float ox = tanhf(fmaf(z.x, w0.x, fmaf(z.y, w1.x, b.x)));
        float oy = tanhf(fmaf(z.x, w0.y, fmaf(z.y, w1.y, b.y)));
        float oz = tanhf(fmaf(z.x, w0.z, fmaf(z.y, w1.z, b.z)));
        float ow = tanhf(fmaf(z.x, w0.w, fmaf(z.y, w1.w, b.w)));
        uint2 pk;
        pk.x = pack_bf16x2(ox, oy);
        pk.y = pack_bf16x2(oz, ow);
        ((uint2*)h)[(qoff + row) * 8 + (q & 7)] = pk;
    }
}

// ---------------- MFMA GEMM: t[4][N][32](bf16) = (A[4][N][32](bf16) @ W) * dinv ----------------

__global__ __launch_bounds__(256) void gemm_mfma(const unsigned short* __restrict__ A,
                                                 const unsigned* __restrict__ Wt,
                                                 const float* __restrict__ dinv,
                                                 unsigned short* __restrict__ t, int N) {
    __shared__ unsigned sW[128 * 68];
    const uint4* Wt4 = (const uint4*)Wt;
    for (int i = threadIdx.x; i < 2048; i += 256) {
        int n = i >> 4, c = i & 15;
        *(uint4*)&sW[n * 68 + c * 4] = Wt4[i];
    }
    __syncthreads();
    int w = threadIdx.x >> 6;
    int l = threadIdx.x & 63;
    int lm = l & 15;
    int q4 = l >> 4;
    int k8 = q4 * 8;

    floatx4 acc[2][8];
#pragma unroll
    for (int i = 0; i < 2; ++i)
#pragma unroll
        for (int j = 0; j < 8; ++j) acc[i][j] = (floatx4){0.f, 0.f, 0.f, 0.f};

    int rowbase = blockIdx.x * 128 + w * 32;
#pragma unroll
    for (int ks = 0; ks < 4; ++ks) {
        short8 a[2];
#pragma unroll
        for (int mt = 0; mt < 2; ++mt) {
            int r = min(rowbase + mt * 16 + lm, N - 1);
            a[mt] = *(const short8*)(A + ((size_t)ks * N + r) * 32 + k8);
        }
#pragma unroll
        for (int nt = 0; nt < 8; ++nt) {
            short8 b = *(const short8*)&sW[(nt * 16 + lm) * 68 + ks * 16 + q4 * 4];
#pragma unroll
            for (int mt = 0; mt < 2; ++mt)
                acc[mt][nt] = __builtin_amdgcn_mfma_f32_16x16x32_bf16(a[mt], b, acc[mt][nt], 0, 0, 0);
        }
    }

#pragma unroll
    for (int mt = 0; mt < 2; ++mt) {
#pragma unroll
        for (int reg = 0; reg < 4; ++reg) {
            int gr = rowbase + mt * 16 + q4 * 4 + reg;
            if (gr >= N) continue;
            float dv = dinv[gr];
#pragma unroll
            for (int nt = 0; nt < 8; ++nt) {
                t[((size_t)(nt >> 1) * N + gr) * 32 + (nt & 1) * 16 + lm] =
                    bf16_1(acc[mt][nt][reg] * dv);
            }
        }
    }
}

// ---------------- layer-2 aggregation: 256 nodes/block (1024 thr), 4 lanes/node -------------
// XCD-affinity swizzle: quarter = (bid%8)>>1, chunk = (bid>>3)*2 + (bid&1).
// Each XCD pair works one quarter -> 3.2 MB gather table resident in that XCD's 4 MB L2.

__global__ __launch_bounds__(1024) void agg_kernel(const unsigned short* __restrict__ t,
                                                   const int* __restrict__ row_ptr,
                                                   const int* __restrict__ bsum,
                                                   const int* __restrict__ col,
                                                   const float* __restrict__ dinv,
                                                   const float* __restrict__ bias,
                                                   unsigned short* __restrict__ out, int N, int E) {
    int nchunk = (N + 255) >> 8;
    int bid = (int)blockIdx.x;
    int r8 = bid & 7;
    int qt = r8 >> 1;                              // feature quarter 0..3 (XCD pair)
    int c = (bid >> 3) * 2 + (r8 & 1);             // node chunk
    if (c >= nchunk) return;
    int q = threadIdx.x & 3;                       // 16B col slot (8 bf16)
    int node = c * 256 + ((int)threadIdx.x >> 2);
    if (node >= N) return;
    const uint4* t4 = (const uint4*)t;
    unsigned qb = (unsigned)qt * (unsigned)N;
    int s = row_ptr[node] + bsum[node >> 10];
    int e = (node + 1 < N) ? row_ptr[node + 1] + bsum[(node + 1) >> 10] : E;
    int deg = e - s;

    float a[8];
    {   // self term
        uint4 v = t4[(size_t)((qb + (unsigned)node) * 4u + q)];
        a[0] = bf16lo(v.x); a[1] = bf16hi(v.x);
        a[2] = bf16lo(v.y); a[3] = bf16hi(v.y);
        a[4] = bf16lo(v.z); a[5] = bf16hi(v.z);
        a[6] = bf16lo(v.w); a[7] = bf16hi(v.w);
    }
    int j = 0;
    for (; j + 4 <= deg; j += 4) {
        int u0 = col[s + j];
        int u1 = col[s + j + 1];
        int u2 = col[s + j + 2];
        int u3 = col[s + j + 3];
        uint4 v0 = t4[(size_t)((qb + (unsigned)u0) * 4u + q)];
        uint4 v1 = t4[(size_t)((qb + (unsigned)u1) * 4u + q)];
        uint4 v2 = t4[(size_t)((qb + (unsigned)u2) * 4u + q)];
        uint4 v3 = t4[(size_t)((qb + (unsigned)u3) * 4u + q)];
        a[0] += bf16lo(v0.x); a[1] += bf16hi(v0.x);
        a[2] += bf16lo(v0.y); a[3] += bf16hi(v0.y);
        a[4] += bf16lo(v0.z); a[5] += bf16hi(v0.z);
        a[6] += bf16lo(v0.w); a[7] += bf16hi(v0.w);
        a[0] += bf16lo(v1.x); a[1] += bf16hi(v1.x);
        a[2] += bf16lo(v1.y); a[3] += bf16hi(v1.y);
        a[4] += bf16lo(v1.z); a[5] += bf16hi(v1.z);
        a[6] += bf16lo(v1.w); a[7] += bf16hi(v1.w);
        a[0] += bf16lo(v2.x); a[1] += bf16hi(v2.x);
        a[2] += bf16lo(v2.y); a[3] += bf16hi(v2.y);
        a[4] += bf16lo(v2.z); a[5] += bf16hi(v2.z);
        a[6] += bf16lo(v2.w); a[7] += bf16hi(v2.w);
        a[0] += bf16lo(v3.x); a[1] += bf16hi(v3.x);
        a[2] += bf16lo(v3.y); a[3] += bf16hi(v3.y);
        a[4] += bf16lo(v3.z); a[5] += bf16hi(v3.z);
        a[6] += bf16lo(v3.w); a[7] += bf16hi(v3.w);
    }
    for (; j < deg; ++j) {
        int u = col[s + j];
        uint4 v = t4[(size_t)((qb + (unsigned)u) * 4u + q)];
        a[0] += bf16lo(v.x); a[1] += bf16hi(v.x);
        a[2] += bf16lo(v.y); a[3] += bf16hi(v.y);
        a[4] += bf16lo(v.z); a[5] += bf16hi(v.z);
        a[6] += bf16lo(v.w); a[7] += bf16hi(v.w);
    }

    float dv = dinv[node];
    const float4* b4 = (const float4*)bias;
    float4 b0 = b4[qt * 8 + q * 2];
    float4 b1 = b4[qt * 8 + q * 2 + 1];
    uint4 pk;
    pk.x = pack_bf16x2(tanhf(fmaf(dv, a[0], b0.x)), tanhf(fmaf(dv, a[1], b0.y)));
    pk.y = pack_bf16x2(tanhf(fmaf(dv, a[2], b0.z)), tanhf(fmaf(dv, a[3], b0.w)));
    pk.z = pack_bf16x2(tanhf(fmaf(dv, a[4], b1.x)), tanhf(fmaf(dv, a[5], b1.y)));
    pk.w = pack_bf16x2(tanhf(fmaf(dv, a[6], b1.z)), tanhf(fmaf(dv, a[7], b1.w)));
    ((uint4*)out)[(size_t)((qb + (unsigned)node) * 4u + q)] = pk;
}

// ---------------- layer-3 aggregation + FUSED pooling (h3 never materialized) ----------------
// Same XCD-affinity swizzle. Per node: fp32 tanh outputs in-register; wave-butterfly max/sum
// when the wave's 16 nodes share a graph (batch sorted), merge via LDS, 128 atomics per block.

__global__ __launch_bounds__(1024) void agg3_pool(const unsigned short* __restrict__ t,
                                                  const int* __restrict__ row_ptr,
                                                  const int* __restrict__ bsum,
                                                  const int* __restrict__ col,
                                                  const float* __restrict__ dinv,
                                                  const float* __restrict__ bias,
                                                  const int* __restrict__ batch,
                                                  unsigned* __restrict__ pmax,
                                                  float* __restrict__ psum, int N, int E) {
    int nchunk = (N + 255) >> 8;
    int bid = (int)blockIdx.x;
    int r8 = bid & 7;
    int qt = r8 >> 1;
    int c = (bid >> 3) * 2 + (r8 & 1);
    if (c >= nchunk) return;

    __shared__ unsigned smax[2][32];
    __shared__ float ssum[2][32];
    if (threadIdx.x < 64) {
        smax[threadIdx.x >> 5][threadIdx.x & 31] = 0u;
        ssum[threadIdx.x >> 5][threadIdx.x & 31] = 0.f;
    }
    __syncthreads();

    int q = threadIdx.x & 3;
    int blockBase = c * 256;
    int node = blockBase + ((int)threadIdx.x >> 2);
    bool valid = node < N;
    int nc = valid ? node : N - 1;
    const uint4* t4 = (const uint4*)t;
    unsigned qb = (unsigned)qt * (unsigned)N;
    int s = row_ptr[nc] + bsum[nc >> 10];
    int e = (nc + 1 < N) ? row_ptr[nc + 1] + bsum[(nc + 1) >> 10] : E;
    int deg = valid ? (e - s) : 0;

    float a[8];
    {   // self term (of nc; discarded for invalid lanes)
        uint4 v = t4[(size_t)((qb + (unsigned)nc) * 4u + q)];
        a[0] = bf16lo(v.x); a[1] = bf16hi(v.x);
        a[2] = bf16lo(v.y); a[3] = bf16hi(v.y);
        a[4] = bf16lo(v.z); a[5] = bf16hi(v.z);
        a[6] = bf16lo(v.w); a[7] = bf16hi(v.w);
    }
    int j = 0;
    for (; j + 4 <= deg; j += 4) {
        int u0 = col[s + j];
        int u1 = col[s + j + 1];
        int u2 = col[s + j + 2];
        int u3 = col[s + j + 3];
        uint4 v0 = t4[(size_t)((qb + (unsigned)u0) * 4u + q)];
        uint4 v1 = t4[(size_t)((qb + (unsigned)u1) * 4u + q)];
        uint4 v2 = t4[(size_t)((qb + (unsigned)u2) * 4u + q)];
        uint4 v3 = t4[(size_t)((qb + (unsigned)u3) * 4u + q)];
        a[0] += bf16lo(v0.x); a[1] += bf16hi(v0.x);
        a[2] += bf16lo(v0.y); a[3] += bf16hi(v0.y);
        a[4] += bf16lo(v0.z); a[5] += bf16hi(v0.z);
        a[6] += bf16lo(v0.w); a[7] += bf16hi(v0.w);
        a[0] += bf16lo(v1.x); a[1] += bf16hi(v1.x);
        a[2] += bf16lo(v1.y); a[3] += bf16hi(v1.y);
        a[4] += bf16lo(v1.z); a[5] += bf16hi(v1.z);
        a[6] += bf16lo(v1.w); a[7] += bf16hi(v1.w);
        a[0] += bf16lo(v2.x); a[1] += bf16hi(v2.x);
        a[2] += bf16lo(v2.y); a[3] += bf16hi(v2.y);
        a[4] += bf16lo(v2.z); a[5] += bf16hi(v2.z);
        a[6] += bf16lo(v2.w); a[7] += bf16hi(v2.w);
        a[0] += bf16lo(v3.x); a[1] += bf16hi(v3.x);
        a[2] += bf16lo(v3.y); a[3] += bf16hi(v3.y);
        a[4] += bf16lo(v3.z); a[5] += bf16hi(v3.z);
        a[6] += bf16lo(v3.w); a[7] += bf16hi(v3.w);
    }
    for (; j < deg; ++j) {
        int u = col[s + j];
        uint4 v = t4[(size_t)((qb + (unsigned)u) * 4u + q)];
        a[0] += bf16lo(v.x); a[1] += bf16hi(v.x);
        a[2] += bf16lo(v.y); a[3] += bf16hi(v.y);
        a[4] += bf16lo(v.z); a[5] += bf16hi(v.z);
        a[6] += bf16lo(v.w); a[7] += bf16hi(v.w);
    }

    float dv = dinv[nc];
    const float4* b4 = (const float4*)bias;
    float4 b0 = b4[qt * 8 + q * 2];
    float4 b1 = b4[qt * 8 + q * 2 + 1];
    float o[8];
    o[0] = tanhf(fmaf(dv, a[0], b0.x)); o[1] = tanhf(fmaf(dv, a[1], b0.y));
    o[2] = tanhf(fmaf(dv, a[2], b0.z)); o[3] = tanhf(fmaf(dv, a[3], b0.w));
    o[4] = tanhf(fmaf(dv, a[4], b1.x)); o[5] = tanhf(fmaf(dv, a[5], b1.y));
    o[6] = tanhf(fmaf(dv, a[6], b1.z)); o[7] = tanhf(fmaf(dv, a[7], b1.w));

    int g = batch[nc];
    int g0 = batch[min(blockBase, N - 1)];
    int gl = __shfl(g, 0, 64);
    int gh = __shfl(g, 63, 64);

    if (gl == gh) {
        // fast path: whole wave in one graph -> butterfly reduce over the 16 node groups
        float m[8], sv[8];
#pragma unroll
        for (int k = 0; k < 8; ++k) {
            m[k] = valid ? o[k] : -3.402823466e+38f;
            sv[k] = valid ? o[k] : 0.f;
        }
#pragma unroll
        for (int st = 4; st < 64; st <<= 1) {
#pragma unroll
            for (int k = 0; k < 8; ++k) {
                m[k] = fmaxf(m[k], __shfl_xor(m[k], st, 64));
                sv[k] += __shfl_xor(sv[k], st, 64);
            }
        }
        if (((threadIdx.x & 63) >> 2) == 0) {   // 4 lanes (q=0..3) hold reduced values
            int seg = gl - g0;
            if (seg < 2) {
#pragma unroll
                for (int k = 0; k < 8; ++k) {
                    atomicMax(&smax[seg][q * 8 + k], fkey(m[k]));
                    atomicAdd(&ssum[seg][q * 8 + k], sv[k]);
                }
            } else {                            // safety net (tiny graphs)
#pragma unroll
                for (int k = 0; k < 8; ++k) {
                    atomicMax(&pmax[gl * 128 + qt * 32 + q * 8 + k], fkey(m[k]));
                    atomicAdd(&psum[gl * 128 + qt * 32 + q * 8 + k], sv[k]);
                }
            }
        }
    } else {
        // boundary wave: per-lane merge
        if (valid) {
            int seg = g - g0;
            if (seg < 2) {
#pragma unroll
                for (int k = 0; k < 8; ++k) {
                    atomicMax(&smax[seg][q * 8 + k], fkey(o[k]));
                    atomicAdd(&ssum[seg][q * 8 + k], o[k]);
                }
            } else {
#pragma unroll
                for (int k = 0; k < 8; ++k) {
                    atomicMax(&pmax[g * 128 + qt * 32 + q * 8 + k], fkey(o[k]));
                    atomicAdd(&psum[g * 128 + qt * 32 + q * 8 + k], o[k]);
                }
            }
        }
    }
    __syncthreads();
    if (threadIdx.x < 64) {
        int seg = threadIdx.x >> 5, cc = threadIdx.x & 31;
        int g0b = batch[min(blockBase, N - 1)];
        int gg = g0b + seg;
        if (gg < NGRAPH) {
            atomicMax(&pmax[gg * 128 + qt * 32 + cc], smax[seg][cc]);
            atomicAdd(&psum[gg * 128 + qt * 32 + cc], ssum[seg][cc]);
        }
    }
}

// ---------------- final: decode pooled accumulators + output head ----------------

__global__ __launch_bounds__(128) void pool_final(const unsigned* __restrict__ pmax,
                                                  const float* __restrict__ psum,
                                                  const int* __restrict__ goff,
                                                  const float* __restrict__ Wo,
                                                  const float* __restrict__ bo,
                                                  float* __restrict__ out) {
    __shared__ float p[256];
    int g = blockIdx.x;
    int j = threadIdx.x;
    int cnt = goff[g + 1] - goff[g];
    unsigned key = pmax[g * 128 + j];
    float mx = (key & 0x80000000u) ? __uint_as_float(key ^ 0x80000000u)
                                   : __uint_as_float(~key);
    p[j] = (cnt > 0) ? mx : 0.f;
    p[128 + j] = psum[g * 128 + j] / fmaxf((float)cnt, 1.f);
    __syncthreads();
    if (j < 41) {
        float acc = bo[j];
        for (int k = 0; k < 256; ++k) acc = fmaf(p[k], Wo[k * 41 + j], acc);
        out[g * 41 + j] = tanhf(acc);
    }
}

// ---------------- launch ----------------

extern "C" void kernel_launch(void* const* d_in, const int* in_sizes, int n_in,
                              void* d_out, int out_size, void* d_ws, size_t ws_size,
                              hipStream_t stream) {
    const float* x   = (const float*)d_in[0];
    const int*   ei  = (const int*)d_in[1];
    const int* batch = (const int*)d_in[2];
    const float* W1  = (const float*)d_in[3];
    const float* b1  = (const float*)d_in[4];
    const float* W2  = (const float*)d_in[5];
    const float* b2  = (const float*)d_in[6];
    const float* W3  = (const float*)d_in[7];
    const float* b3  = (const float*)d_in[8];
    const float* Wo  = (const float*)d_in[9];
    const float* bo  = (const float*)d_in[10];
    float* outp = (float*)d_out;

    int N = in_sizes[2];
    int E = in_sizes[1] / 2;
    const int* src = ei;
    const int* dst = ei + E;

    char* p = (char*)d_ws;
    auto alloc = [&](size_t bytes) -> char* {
        char* q = p;
        p += (bytes + 255) & ~(size_t)255;
        return q;
    };
    unsigned short* t   = (unsigned short*)alloc((size_t)N * 128 * 2);  // bf16 gemm out [4][N][32]
    unsigned short* hb  = (unsigned short*)alloc((size_t)N * 128 * 2);  // bf16 h1 / h2  [4][N][32]
    float* dinv   = (float*)alloc((size_t)N * 4);
    int*   rowp   = (int*)alloc((size_t)(N + 1) * 4);
    int*   col    = (int*)alloc((size_t)E * 4);
    int*   goff   = (int*)alloc(65 * 4);
    float2* y     = (float2*)alloc((size_t)N * 8);
    unsigned* Wt2 = (unsigned*)alloc(128 * 64 * 4);
    unsigned* Wt3 = (unsigned*)alloc(128 * 64 * 4);
    int nscan = (N + SCAN_BLK - 1) / SCAN_BLK;
    int*   bsum   = (int*)alloc((size_t)nscan * 4);
    // zero-init region: cnt | ticket | pmax | psum (single memset)
    size_t cntB = ((size_t)N * 4 + 255) & ~(size_t)255;
    char* zbase = alloc(cntB + 256 + NGRAPH * 128 * 4 * 2);
    int*      cnt  = (int*)zbase;
    int*      tick = (int*)(zbase + cntB);
    unsigned* pmax = (unsigned*)(zbase + cntB + 256);
    float*    psum = (float*)(zbase + cntB + 256 + NGRAPH * 128 * 4);

    (void)hipMemsetAsync(zbase, 0, cntB + 256 + NGRAPH * 128 * 4 * 2, stream);

    pack_count<<<32 + (E + 255) / 256, 256, 0, stream>>>(dst, E, cnt, W2, W3, Wt2, Wt3);
    scanA<<<nscan, SCAN_BLK, 0, stream>>>(cnt, x, rowp, bsum, dinv, y, batch, tick, goff, N);
    fill_kernel<<<(E + 255) / 256, 256, 0, stream>>>(src, dst, E, rowp, bsum, cnt, col);

    // agg grid: XCD-affinity swizzled flat grid (see agg_kernel)
    int nchunk = (N + 255) >> 8;
    int nchunkR = (nchunk + 1) & ~1;         // round up to even
    int nblk = nchunkR * 4;                  // = (nchunkR/2) * 8, multiple of 8

    // layer 1: fused agg(x) + transform -> h1 (bf16, quarter-major)
    agg_x_t1<<<(N + 255) / 256, 256, 0, stream>>>(y, rowp, bsum, col, dinv, W1, b1, hb, N, E);
    // layer 2
    gemm_mfma<<<(N + 127) / 128, 256, 0, stream>>>(hb, Wt2, dinv, t, N);
    agg_kernel<<<nblk, 1024, 0, stream>>>(t, rowp, bsum, col, dinv, b2, hb, N, E);
    // layer 3 (pooling fused into agg)
    gemm_mfma<<<(N + 127) / 128, 256, 0, stream>>>(hb, Wt3, dinv, t, N);
    agg3_pool<<<nblk, 1024, 0, stream>>>(t, rowp, bsum, col, dinv, b3, batch, pmax, psum, N, E);

    pool_final<<<NGRAPH, 128, 0, stream>>>(pmax, psum, goff, Wo, bo, outp);
}